// Round 11
// baseline (358.823 us; speedup 1.0000x reference)
//
#include <hip/hip_runtime.h>
#include <hip/hip_bf16.h>

typedef unsigned short ushortT;
typedef short short8v __attribute__((ext_vector_type(8)));
typedef float float4v __attribute__((ext_vector_type(4)));

// Problem constants
#define NBL 6      // B*LEN
#define NC 64
#define NC3 192
#define NHW 4096   // 64*64
#define NDI 128
#define NNS 16
#define NDR 4
#define NK 4
#define NL 4096
#define NCH 128    // scan chunks
#define SCLEN 32   // chunk length
#define NSTATE 49152  // 24 bk * 128 d * 16 n

// workspace offsets in floats
static const size_t F_XCAT  = 0;          // 4,718,592 (wt_ip after skip; chunkHS span during scan)
static const size_t F_ACT1  = 4718592;    // act1b bf16 NHWC; wt_sk after conv1; chunkHS tail
static const size_t F_H1    = 9437184;    // 1,572,864
static const size_t F_ACT2  = 11010048;   // act2b bf16 NHWC
static const size_t F_H2    = 12582912;   // 1,572,864
static const size_t F_XRES  = 14155776;   // 1,572,864
static const size_t F_XXIN  = 15728640;   // 3,145,728 (wt_op/f1/f2 after dwconv)
static const size_t F_Z     = 18874368;   // 3,145,728
static const size_t F_XXC   = 22020096;   // 3,145,728
static const size_t F_XDBL  = 25165824;   // 3,538,944
static const size_t F_YS    = 28704768;   // 12,582,912 (chunkH+chunkSdt during scan; ys after)
static const size_t F_YCOMB = 41287680;   // 3,145,728 (unused now)
static const size_t F_X1    = 44433408;   // 1,572,864
static const size_t F_X2    = 46006272;   // 1,572,864 (stats partials + conv wpacks early)
static const size_t F_STATS = 47579136;   // 48
static const size_t F_TOTAL = 47579184;   // floats (~190.3 MB)

__device__ __forceinline__ float wred64(float v) {
#pragma unroll
  for (int m = 32; m; m >>= 1) v += __shfl_xor(v, m, 64);
  return v;
}

__device__ __forceinline__ float silu(float v) {
  return v / (1.f + __expf(-v));
}

__device__ __forceinline__ ushortT f2bf(float f) {
  unsigned int u = __builtin_bit_cast(unsigned int, f);
  unsigned int r = (u + 0x7FFFu + ((u >> 16) & 1u)) >> 16;
  return (ushortT)r;
}

__device__ __forceinline__ int map_pos(int k, int l) {
  if (k == 0) return l;
  if (k == 1) return ((l & 63) << 6) | (l >> 6);
  if (k == 2) return 4095 - l;
  int lp = 4095 - l;
  return ((lp & 63) << 6) | (lp >> 6);
}

// softplus via hw exp2/log2: ln(1+e^a) = ln2 * log2(1 + 2^(a*log2e))
__device__ __forceinline__ float softplus_fast(float a) {
  float t = exp2f(a * 1.44269504f);
  float r = 0.69314718f * __log2f(1.f + t);
  return (a > 20.f) ? a : r;
}

// powers E^1..E^16 via mul tree (for geometric A: a_n = (n+1)*a_1)
__device__ __forceinline__ void pow_tree(float E1, float4v& e0, float4v& e1,
                                         float4v& e2, float4v& e3) {
  float E2 = E1 * E1, E3 = E2 * E1, E4 = E2 * E2;
  float E5 = E4 * E1, E6 = E4 * E2, E7 = E4 * E3, E8 = E4 * E4;
  e0[0] = E1; e0[1] = E2; e0[2] = E3; e0[3] = E4;
  e1[0] = E5; e1[1] = E6; e1[2] = E7; e1[3] = E8;
  e2[0] = E8 * E1; e2[1] = E8 * E2; e2[2] = E8 * E3; e2[3] = E8 * E4;
  e3[0] = E8 * E5; e3[1] = E8 * E6; e3[2] = E8 * E7; e3[3] = E8 * E8;
}

// generic weight transpose: dst[c*O + o] = src[o*C + c]
__global__ __launch_bounds__(256) void wtrans_kernel(const float* __restrict__ src,
                                                     float* __restrict__ dst, int O, int C) {
  int id = blockIdx.x * 256 + threadIdx.x;
  if (id >= O * C) return;
  int c = id / O, o = id % O;
  dst[id] = src[o * C + c];
}

// ---- two-stage per-sample mean/rstd (f64 accumulate) ----
__global__ __launch_bounds__(256) void stats1_kernel(const float* __restrict__ in, int n,
                                                     double* __restrict__ part) {
  int bi = blockIdx.x;
  int s = bi >> 5, j = bi & 31;
  int slice = n >> 5;
  const float4* p = (const float4*)(in + (size_t)s * n + (size_t)j * slice);
  int n4 = slice >> 2;
  double dsum = 0.0, dsq = 0.0;
  for (int i = threadIdx.x; i < n4; i += 256) {
    float4 v = p[i];
    dsum += (double)((v.x + v.y) + (v.z + v.w));
    dsq += (double)v.x * v.x + (double)v.y * v.y + (double)v.z * v.z + (double)v.w * v.w;
  }
  __shared__ double s1[256], s2[256];
  s1[threadIdx.x] = dsum; s2[threadIdx.x] = dsq;
  __syncthreads();
  for (int off = 128; off; off >>= 1) {
    if (threadIdx.x < off) { s1[threadIdx.x] += s1[threadIdx.x + off]; s2[threadIdx.x] += s2[threadIdx.x + off]; }
    __syncthreads();
  }
  if (threadIdx.x == 0) { part[2 * bi] = s1[0]; part[2 * bi + 1] = s2[0]; }
}

__global__ __launch_bounds__(64) void stats2_kernel(const double* __restrict__ part, int n,
                                                    float* __restrict__ mean_out,
                                                    float* __restrict__ rstd_out) {
  int s = blockIdx.x;
  int lane = threadIdx.x;
  double sum = 0.0, sq = 0.0;
  if (lane < 32) { sum = part[2 * (s * 32 + lane)]; sq = part[2 * (s * 32 + lane) + 1]; }
#pragma unroll
  for (int m = 16; m; m >>= 1) { sum += __shfl_xor(sum, m, 64); sq += __shfl_xor(sq, m, 64); }
  if (lane == 0) {
    double mean = sum / n;
    double var = sq / n - mean * mean;
    mean_out[s] = (float)mean;
    rstd_out[s] = (float)(1.0 / sqrt(var + 1e-5));
  }
}

// x_cat[bl][ch][p]: ch<64 dz, 64..127 instance-normed img, 128..191 sigma
__global__ __launch_bounds__(256) void build_xcat_kernel(const float* __restrict__ img,
                                                         const float* __restrict__ dz,
                                                         const float* __restrict__ sg,
                                                         const float* __restrict__ stats,
                                                         float* __restrict__ xcat) {
  size_t gid = (size_t)blockIdx.x * 256 + threadIdx.x;
  int p = gid & 4095;
  size_t r = gid >> 12;
  int ch = (int)(r % NC3);
  int bl = (int)(r / NC3);
  int b = bl / 3;
  float v;
  if (ch < 64) {
    v = dz[((size_t)b * NC + ch) * NHW + p];
  } else if (ch < 128) {
    float m = stats[bl], rs = stats[8 + bl];
    v = (img[((size_t)bl * NC + (ch - 64)) * NHW + p] - m) * rs;
  } else {
    v = sg[((size_t)b * NC + (ch - 128)) * NHW + p];
  }
  xcat[gid] = v;
}

// GN + SiLU + NCHW->NHWC transpose + f32->bf16. grid NBL*64, block 256.
template <int CCH>
__global__ __launch_bounds__(256) void gnsilu_t_kernel(const float* __restrict__ in,
                                                       const float* __restrict__ g,
                                                       const float* __restrict__ b,
                                                       const float* __restrict__ stats,
                                                       ushortT* __restrict__ outb) {
  int bi = blockIdx.x;
  int bl = bi >> 6, h = bi & 63;
  __shared__ ushortT tile[CCH][66];
  float m = stats[bl], rs = stats[8 + bl];
  int t = threadIdx.x;
  for (int idx = t; idx < CCH * 64; idx += 256) {
    int ch = idx >> 6, w = idx & 63;
    float v = in[(((size_t)bl * CCH + ch) << 12) + (h << 6) + w];
    v = (v - m) * rs * g[ch] + b[ch];
    v = silu(v);
    tile[ch][w] = f2bf(v);
  }
  __syncthreads();
  constexpr int C8 = CCH / 8;
  for (int idx = t; idx < 64 * C8; idx += 256) {
    int w = idx / C8, c8 = idx % C8;
    short8v v;
#pragma unroll
    for (int j = 0; j < 8; ++j) v[j] = (short)tile[c8 * 8 + j][w];
    *(short8v*)&outb[(size_t)(bl * 4096 + h * 64 + w) * CCH + c8 * 8] = v;
  }
}

// Pre-pack conv weights into per-lane MFMA B-fragments (bf16).
__global__ __launch_bounds__(256) void wprep_kernel(const float* __restrict__ w,
                                                    ushortT* __restrict__ out,
                                                    int CIN, int KT) {
  int id = blockIdx.x * 256 + threadIdx.x;
  int j = id & 7;
  int lane = (id >> 3) & 63;
  int nt = (id >> 9) & 3;
  int rest = id >> 11;
  int kt = rest % KT;
  int tap = rest / KT;
  int oc = nt * 16 + (lane & 15);
  int ic = kt * 32 + ((lane >> 4) << 3) + j;
  int r = tap / 3, s = tap % 3;
  out[id] = f2bf(w[(((size_t)oc * CIN + ic) * 3 + r) * 3 + s]);
}

// Implicit-GEMM 3x3 SAME conv via bf16 MFMA, f32 accumulate.
template <int CIN>
__global__ __launch_bounds__(256) void conv_mfma_kernel(const ushortT* __restrict__ actb,
                                                        const ushortT* __restrict__ wb,
                                                        const float* __restrict__ bias,
                                                        float* __restrict__ out) {
  constexpr int KT = CIN / 32;
  constexpr int STRIDE = CIN + 8;
  constexpr int C8 = CIN / 8;
  int bi = blockIdx.x;
  int nh = bi & 1;
  int h = (bi >> 1) & 63;
  int bl = bi >> 7;
  int t = threadIdx.x;
  int wv = t >> 6, lane = t & 63;
  __shared__ ushortT lds[66 * STRIDE];
  float4v acc0 = {0.f, 0.f, 0.f, 0.f};
  float4v acc1 = {0.f, 0.f, 0.f, 0.f};
  int lrow = lane & 15;
  int lk = (lane >> 4) << 3;
  for (int dy = 0; dy < 3; ++dy) {
    int hh = h + dy - 1;
    bool valid = (hh >= 0) && (hh < 64);
    int hc = valid ? hh : 0;
    if (dy) __syncthreads();
    const ushortT* src = actb + (size_t)(bl * 4096 + hc * 64) * CIN;
    for (int idx = t; idx < 64 * C8; idx += 256) {
      int w = idx / C8, c8 = idx % C8;
      short8v v = {0, 0, 0, 0, 0, 0, 0, 0};
      if (valid) v = *(const short8v*)&src[(size_t)w * CIN + c8 * 8];
      *(short8v*)&lds[(w + 1) * STRIDE + c8 * 8] = v;
    }
    if (t < 2 * C8) {
      int which = t / C8, c8 = t % C8;
      short8v z = {0, 0, 0, 0, 0, 0, 0, 0};
      *(short8v*)&lds[(which ? 65 : 0) * STRIDE + c8 * 8] = z;
    }
    __syncthreads();
    for (int dx = 0; dx < 3; ++dx) {
      int tap = dy * 3 + dx;
      int wl = (wv << 4) + lrow + dx;
#pragma unroll
      for (int kt = 0; kt < KT; ++kt) {
        short8v a = *(const short8v*)&lds[wl * STRIDE + kt * 32 + lk];
        const ushortT* wp = wb + ((size_t)(((tap * KT + kt) * 4 + (nh << 1)) * 64 + lane) << 3);
        short8v b0 = *(const short8v*)&wp[0];
        short8v b1 = *(const short8v*)&wp[512];
        acc0 = __builtin_amdgcn_mfma_f32_16x16x32_bf16(a, b0, acc0, 0, 0, 0);
        acc1 = __builtin_amdgcn_mfma_f32_16x16x32_bf16(a, b1, acc1, 0, 0, 0);
      }
    }
  }
  int oc0 = (nh << 5) + lrow;
  int oc1 = oc0 + 16;
  int w0 = (wv << 4) + ((lane >> 4) << 2);
  float bv0 = bias[oc0], bv1 = bias[oc1];
  float4 o0 = make_float4(acc0[0] + bv0, acc0[1] + bv0, acc0[2] + bv0, acc0[3] + bv0);
  float4 o1 = make_float4(acc1[0] + bv1, acc1[1] + bv1, acc1[2] + bv1, acc1[3] + bv1);
  *(float4*)&out[(((size_t)bl * 64 + oc0) << 12) + (h << 6) + w0] = o0;
  *(float4*)&out[(((size_t)bl * 64 + oc1) << 12) + (h << 6) + w0] = o1;
}

// x_res[bl][p][oc] = h2[bl][oc][p] + 1x1skip(xcat)[oc] + skb[oc]   (NHWC out)
__global__ __launch_bounds__(256) void skip_kernel(const float* __restrict__ xcat,
                                                   const float* __restrict__ h2,
                                                   const float* __restrict__ skwt,
                                                   const float* __restrict__ skb,
                                                   float* __restrict__ xres) {
  int bi = blockIdx.x;
  int bl = bi >> 6, h = bi & 63;
  int t = threadIdx.x;
  int oc = t & 63, w0 = (t >> 6) << 4;
  __shared__ float lds[64][64];
  float acc[16];
#pragma unroll
  for (int i = 0; i < 16; ++i) acc[i] = 0.f;
  for (int cc = 0; cc < 3; ++cc) {
    __syncthreads();
    for (int idx = t; idx < 4096; idx += 256) {
      int ch = idx >> 6, w = idx & 63;
      lds[ch][w] = xcat[(((size_t)bl * NC3 + cc * 64 + ch) << 12) + (h << 6) + w];
    }
    __syncthreads();
    for (int ch = 0; ch < 64; ++ch) {
      float wv = skwt[((cc << 6) + ch) * 64 + oc];
#pragma unroll
      for (int i = 0; i < 16; ++i) acc[i] += wv * lds[ch][w0 + i];
    }
  }
  float bv = skb[oc];
  int p0 = (h << 6) + w0;
#pragma unroll
  for (int i = 0; i < 16; ++i) {
    float hv = h2[(((size_t)bl * 64 + oc) << 12) + p0 + i];
    xres[((size_t)bl * NHW + p0 + i) * 64 + oc] = acc[i] + bv + hv;
  }
}

// LN(ln1) + 64->256 proj; 16 positions per block; wt[c(64)][oc(256)]. grid 1536.
__global__ __launch_bounds__(256) void inproj_kernel(const float* __restrict__ xres,
                                                     const float* __restrict__ g,
                                                     const float* __restrict__ b,
                                                     const float* __restrict__ wt,
                                                     float* __restrict__ xxin,
                                                     float* __restrict__ z) {
  int wv = threadIdx.x >> 6, lane = threadIdx.x & 63;
  size_t pi0 = (size_t)blockIdx.x << 4;
  __shared__ float xb[64][16];
  float gv = g[lane], bv = b[lane];
#pragma unroll
  for (int j = 0; j < 4; ++j) {
    int p = (wv << 2) + j;
    float x = xres[(pi0 + p) * 64 + lane];
    float s = wred64(x);
    float s2 = wred64(x * x);
    float m = s * (1.f / 64), var = s2 * (1.f / 64) - m * m;
    float rstd = rsqrtf(var + 1e-5f);
    xb[lane][p] = (x - m) * rstd * gv + bv;
  }
  __syncthreads();
  int oc = (wv << 6) + lane;
  float4v a0 = {0.f, 0.f, 0.f, 0.f}, a1 = a0, a2 = a0, a3 = a0;
  for (int c = 0; c < 64; ++c) {
    float w = wt[(c << 8) + oc];
    const float4v* xr = (const float4v*)&xb[c][0];
    a0 += w * xr[0];
    a1 += w * xr[1];
    a2 += w * xr[2];
    a3 += w * xr[3];
  }
  float acc[16];
  *(float4v*)&acc[0] = a0;
  *(float4v*)&acc[4] = a1;
  *(float4v*)&acc[8] = a2;
  *(float4v*)&acc[12] = a3;
  float* dst = (oc < 128) ? xxin : z;
  int oco = (oc < 128) ? oc : (oc - 128);
#pragma unroll
  for (int p = 0; p < 16; ++p) dst[((pi0 + p) << 7) + oco] = acc[p];
}

// depthwise 3x3 SAME + bias + silu on NHWC [bl][p][128]
__global__ __launch_bounds__(256) void dwconv_kernel(const float* __restrict__ xx,
                                                     const float* __restrict__ w,
                                                     const float* __restrict__ b,
                                                     float* __restrict__ out) {
  size_t gid = (size_t)blockIdx.x * 256 + threadIdx.x;
  int d = gid & 127;
  size_t pi = gid >> 7;
  int p = (int)(pi & 4095);
  int bl = (int)(pi >> 12);
  int h = p >> 6, wq = p & 63;
  float acc = b[d];
  const float* wr = w + d * 9;
#pragma unroll
  for (int dy = -1; dy <= 1; ++dy) {
    int hh = h + dy;
    if (hh < 0 || hh >= 64) continue;
#pragma unroll
    for (int dx = -1; dx <= 1; ++dx) {
      int ww = wq + dx;
      if (ww < 0 || ww >= 64) continue;
      acc += wr[(dy + 1) * 3 + (dx + 1)] * xx[(((size_t)bl << 12) + (hh << 6) + ww) * 128 + d];
    }
  }
  out[pi * 128 + d] = silu(acc);
}

// x_dbl via shared hw/wh tile; computes forward k and reversed k+2 per block.
__global__ __launch_bounds__(256) void xdbl_kernel(const float* __restrict__ xxc,
                                                   const float* __restrict__ xpw,
                                                   float* __restrict__ xdbl) {
  int bi = blockIdx.x;
  int lt = bi & 63;
  int korder = (bi >> 6) & 1;
  int bl = bi >> 7;
  int lbase = lt << 6;
  __shared__ float xs[64 * 128];  // row l (stride 128), slot-swizzled float4s
  int t = threadIdx.x;
#pragma unroll
  for (int it = 0; it < 8; ++it) {
    int idx = it * 256 + t;
    int i = idx >> 5, d4 = idx & 31;
    int l = lbase + i;
    int pos = korder ? (((l & 63) << 6) | (l >> 6)) : l;
    float4 v = *(const float4*)&xxc[((size_t)bl * NHW + pos) * 128 + (d4 << 2)];
    int slot = d4 ^ (i & 7);
    *(float4*)&xs[i * 128 + (slot << 2)] = v;
  }
  __syncthreads();
  int wv = __builtin_amdgcn_readfirstlane(t >> 6);
  int lane = t & 63;
  int k_w = korder + ((wv >= 2) ? 2 : 0);
  int c0 = (wv & 1) * 18;
  float acc[18];
#pragma unroll
  for (int j = 0; j < 18; ++j) acc[j] = 0.f;
  const float* wbase = xpw + (size_t)(k_w * 36 + c0) * 128;
  for (int d4 = 0; d4 < 32; ++d4) {
    int slot = d4 ^ (lane & 7);
    float4 x4 = *(const float4*)&xs[lane * 128 + (slot << 2)];
#pragma unroll
    for (int j = 0; j < 18; ++j) {
      float4 w4 = *(const float4*)&wbase[j * 128 + (d4 << 2)];
      acc[j] += w4.x * x4.x + w4.y * x4.y + w4.z * x4.z + w4.w * x4.w;
    }
  }
  int lout = (k_w < 2) ? (lbase + lane) : (4095 - lbase - lane);
  size_t obase = ((size_t)(bl * 4 + k_w) * 36 + c0) * (size_t)NL + lout;
#pragma unroll
  for (int j = 0; j < 18; ++j)
    xdbl[obase + (size_t)j * NL] = acc[j];
}

// ---- chunked selective scan ----
// Pass 1: local scan; store end-state H (16/thread) + sdt scalar (P recomputed in pass2).
__global__ __launch_bounds__(128) void scan_pass1_kernel(const float* __restrict__ xdbl,
                                                         const float* __restrict__ xxc,
                                                         const float* __restrict__ dtw,
                                                         const float* __restrict__ dtb,
                                                         const float* __restrict__ Alog,
                                                         float* __restrict__ chunkSdt,
                                                         float* __restrict__ chunkH) {
  int bi = blockIdx.x;
  int chunk = bi & (NCH - 1);
  int bk = bi >> 7;
  int k = bk & 3, bl = bk >> 2;
  int d = threadIdx.x;
  float4 wv = *(const float4*)(dtw + (size_t)(((k << 7) + d) << 2));
  float bias = dtb[(k << 7) + d];
  const float* ar = Alog + (size_t)(((k << 7) + d) << 4);
  float a1v = -__expf(ar[0]) * 1.44269504f;
  bool geom = true;
#pragma unroll
  for (int n = 1; n < 16; ++n) {
    float an = -__expf(ar[n]) * 1.44269504f;
    geom = geom && (fabsf(an - (float)(n + 1) * a1v) <= 1e-3f * fabsf((float)(n + 1) * a1v) + 1e-6f);
  }
  __shared__ float xd[SCLEN][20];
  int l0 = chunk << 5;
  for (int idx = threadIdx.x; idx < 20 * SCLEN; idx += 128) {
    int c = idx >> 5, li = idx & 31;
    xd[li][c] = xdbl[((size_t)bk * 36 + c) * (size_t)NL + l0 + li];
  }
  __syncthreads();
  const float* uB = xxc + ((size_t)bl << 19) + d;
  float4v h0 = {0.f, 0.f, 0.f, 0.f}, h1 = h0, h2 = h0, h3 = h0;
  float sdt = 0.f;
  float u_nxt = uB[(size_t)map_pos(k, l0) << 7];
  if (geom) {
    for (int li = 0; li < SCLEN; ++li) {
      float u = u_nxt;
      int nl = (li < SCLEN - 1) ? (li + 1) : (SCLEN - 1);
      u_nxt = uB[(size_t)map_pos(k, l0 + nl) << 7];
      const float4v* row = (const float4v*)&xd[li][0];
      float4v q0 = row[0];
      float accq = bias + wv.x * q0[0] + wv.y * q0[1] + wv.z * q0[2] + wv.w * q0[3];
      float dt = softplus_fast(accq);
      float dtu = dt * u;
      sdt += dt;
      float4v b0 = row[1], b1 = row[2], b2 = row[3], b3 = row[4];
      float4v e0, e1, e2, e3;
      pow_tree(exp2f(a1v * dt), e0, e1, e2, e3);
      h0 = e0 * h0 + dtu * b0;
      h1 = e1 * h1 + dtu * b1;
      h2 = e2 * h2 + dtu * b2;
      h3 = e3 * h3 + dtu * b3;
    }
  } else {
    float4v a0v, a1q, a2q, a3q;
#pragma unroll
    for (int j = 0; j < 4; ++j) {
      a0v[j] = -__expf(ar[j]) * 1.44269504f;
      a1q[j] = -__expf(ar[4 + j]) * 1.44269504f;
      a2q[j] = -__expf(ar[8 + j]) * 1.44269504f;
      a3q[j] = -__expf(ar[12 + j]) * 1.44269504f;
    }
    for (int li = 0; li < SCLEN; ++li) {
      float u = u_nxt;
      int nl = (li < SCLEN - 1) ? (li + 1) : (SCLEN - 1);
      u_nxt = uB[(size_t)map_pos(k, l0 + nl) << 7];
      const float4v* row = (const float4v*)&xd[li][0];
      float4v q0 = row[0];
      float accq = bias + wv.x * q0[0] + wv.y * q0[1] + wv.z * q0[2] + wv.w * q0[3];
      float dt = softplus_fast(accq);
      float dtu = dt * u;
      sdt += dt;
      float4v b0 = row[1], b1 = row[2], b2 = row[3], b3 = row[4];
      float4v e0, e1, e2, e3;
#pragma unroll
      for (int j = 0; j < 4; ++j) {
        e0[j] = exp2f(a0v[j] * dt);
        e1[j] = exp2f(a1q[j] * dt);
        e2[j] = exp2f(a2q[j] * dt);
        e3[j] = exp2f(a3q[j] * dt);
      }
      h0 = e0 * h0 + dtu * b0;
      h1 = e1 * h1 + dtu * b1;
      h2 = e2 * h2 + dtu * b2;
      h3 = e3 * h3 + dtu * b3;
    }
  }
  size_t base = (size_t)chunk * NSTATE + (((size_t)bk << 7) + (size_t)d) * 16;
  chunkSdt[(size_t)chunk * 3072 + (bk << 7) + d] = sdt;
  *(float4v*)&chunkH[base + 0] = h0;
  *(float4v*)&chunkH[base + 4] = h1;
  *(float4v*)&chunkH[base + 8] = h2;
  *(float4v*)&chunkH[base + 12] = h3;
}

// Pass 2: per-state combine; P recomputed from sdt. grid 192 x 256.
__global__ __launch_bounds__(256) void scan_pass2_kernel(const float* __restrict__ chunkSdt,
                                                         const float* __restrict__ chunkH,
                                                         const float* __restrict__ Alog,
                                                         float* __restrict__ chunkHS) {
  size_t state = (size_t)blockIdx.x * 256 + threadIdx.x;  // < 49152
  float an = -__expf(Alog[state & 8191]) * 1.44269504f;
  int kd = (int)(state >> 4);  // (bk<<7)+d
  float h = 0.f;
  for (int j = 0; j < NCH; ++j) {
    size_t idx = (size_t)j * NSTATE + state;
    chunkHS[idx] = h;
    float sdt = chunkSdt[(size_t)j * 3072 + kd];
    h = exp2f(an * sdt) * h + chunkH[idx];
  }
}

__global__ __launch_bounds__(128) void scan_pass3_kernel(const float* __restrict__ xdbl,
                                                         const float* __restrict__ xxc,
                                                         const float* __restrict__ dtw,
                                                         const float* __restrict__ dtb,
                                                         const float* __restrict__ Alog,
                                                         const float* __restrict__ chunkHS,
                                                         float* __restrict__ ys) {
  int bi = blockIdx.x;
  int chunk = bi & (NCH - 1);
  int bk = bi >> 7;
  int k = bk & 3, bl = bk >> 2;
  int d = threadIdx.x;
  float4 wv = *(const float4*)(dtw + (size_t)(((k << 7) + d) << 2));
  float bias = dtb[(k << 7) + d];
  const float* ar = Alog + (size_t)(((k << 7) + d) << 4);
  float a1v = -__expf(ar[0]) * 1.44269504f;
  bool geom = true;
#pragma unroll
  for (int n = 1; n < 16; ++n) {
    float an = -__expf(ar[n]) * 1.44269504f;
    geom = geom && (fabsf(an - (float)(n + 1) * a1v) <= 1e-3f * fabsf((float)(n + 1) * a1v) + 1e-6f);
  }
  __shared__ float xd[SCLEN][36];
  int l0 = chunk << 5;
  for (int idx = threadIdx.x; idx < 36 * SCLEN; idx += 128) {
    int c = idx >> 5, li = idx & 31;
    xd[li][c] = xdbl[((size_t)bk * 36 + c) * (size_t)NL + l0 + li];
  }
  __syncthreads();
  const float* uB = xxc + ((size_t)bl << 19) + d;
  float* yB = ys + ((size_t)bk << 19) + d;
  size_t base = (size_t)chunk * NSTATE + (((size_t)bk << 7) + (size_t)d) * 16;
  float4v h0 = *(const float4v*)&chunkHS[base + 0];
  float4v h1 = *(const float4v*)&chunkHS[base + 4];
  float4v h2 = *(const float4v*)&chunkHS[base + 8];
  float4v h3 = *(const float4v*)&chunkHS[base + 12];
  float u_nxt = uB[(size_t)map_pos(k, l0) << 7];
  if (geom) {
    for (int li = 0; li < SCLEN; ++li) {
      float u = u_nxt;
      int nl = (li < SCLEN - 1) ? (li + 1) : (SCLEN - 1);
      u_nxt = uB[(size_t)map_pos(k, l0 + nl) << 7];
      const float4v* row = (const float4v*)&xd[li][0];
      float4v q0 = row[0];
      float accq = bias + wv.x * q0[0] + wv.y * q0[1] + wv.z * q0[2] + wv.w * q0[3];
      float dt = softplus_fast(accq);
      float dtu = dt * u;
      float4v b0 = row[1], b1 = row[2], b2 = row[3], b3 = row[4];
      float4v c0 = row[5], c1 = row[6], c2 = row[7], c3 = row[8];
      float4v e0, e1, e2, e3;
      pow_tree(exp2f(a1v * dt), e0, e1, e2, e3);
      h0 = e0 * h0 + dtu * b0;
      h1 = e1 * h1 + dtu * b1;
      h2 = e2 * h2 + dtu * b2;
      h3 = e3 * h3 + dtu * b3;
      float4v sy = h0 * c0;
      sy += h1 * c1;
      sy += h2 * c2;
      sy += h3 * c3;
      yB[(size_t)(l0 + li) << 7] = (sy[0] + sy[1]) + (sy[2] + sy[3]);
    }
  } else {
    float4v a0v, a1q, a2q, a3q;
#pragma unroll
    for (int j = 0; j < 4; ++j) {
      a0v[j] = -__expf(ar[j]) * 1.44269504f;
      a1q[j] = -__expf(ar[4 + j]) * 1.44269504f;
      a2q[j] = -__expf(ar[8 + j]) * 1.44269504f;
      a3q[j] = -__expf(ar[12 + j]) * 1.44269504f;
    }
    for (int li = 0; li < SCLEN; ++li) {
      float u = u_nxt;
      int nl = (li < SCLEN - 1) ? (li + 1) : (SCLEN - 1);
      u_nxt = uB[(size_t)map_pos(k, l0 + nl) << 7];
      const float4v* row = (const float4v*)&xd[li][0];
      float4v q0 = row[0];
      float accq = bias + wv.x * q0[0] + wv.y * q0[1] + wv.z * q0[2] + wv.w * q0[3];
      float dt = softplus_fast(accq);
      float dtu = dt * u;
      float4v b0 = row[1], b1 = row[2], b2 = row[3], b3 = row[4];
      float4v c0 = row[5], c1 = row[6], c2 = row[7], c3 = row[8];
      float4v e0, e1, e2, e3;
#pragma unroll
      for (int j = 0; j < 4; ++j) {
        e0[j] = exp2f(a0v[j] * dt);
        e1[j] = exp2f(a1q[j] * dt);
        e2[j] = exp2f(a2q[j] * dt);
        e3[j] = exp2f(a3q[j] * dt);
      }
      h0 = e0 * h0 + dtu * b0;
      h1 = e1 * h1 + dtu * b1;
      h2 = e2 * h2 + dtu * b2;
      h3 = e3 * h3 + dtu * b3;
      float4v sy = h0 * c0;
      sy += h1 * c1;
      sy += h2 * c2;
      sy += h3 * c3;
      yB[(size_t)(l0 + li) << 7] = (sy[0] + sy[1]) + (sy[2] + sy[3]);
    }
  }
}

// Fused: 4-direction combine + D*xxc + out_norm LN(128) -> *silu(z) -> out_proj -> +x_res
// 16 pos/block; wt[c(128)][oc(64)]. grid 1536.
__global__ __launch_bounds__(256) void outproj_kernel(const float* __restrict__ ys,
                                                      const float* __restrict__ xxc,
                                                      const float* __restrict__ Ds,
                                                      const float* __restrict__ z,
                                                      const float* __restrict__ ong,
                                                      const float* __restrict__ onb,
                                                      const float* __restrict__ opwt,
                                                      const float* __restrict__ xres,
                                                      float* __restrict__ x1) {
  int wv = threadIdx.x >> 6, lane = threadIdx.x & 63;
  size_t pi0 = (size_t)blockIdx.x << 4;
  __shared__ float gb[128][16];
  float og0 = ong[lane], ob0 = onb[lane];
  float og1 = ong[64 + lane], ob1 = onb[64 + lane];
  float ds0 = Ds[lane] + Ds[128 + lane] + Ds[256 + lane] + Ds[384 + lane];
  float ds1 = Ds[64 + lane] + Ds[192 + lane] + Ds[320 + lane] + Ds[448 + lane];
#pragma unroll
  for (int j = 0; j < 4; ++j) {
    int p = (wv << 2) + j;
    size_t pp = pi0 + p;
    int bl = (int)(pp >> 12);
    int pg = (int)(pp & 4095);
    int h = pg >> 6, w = pg & 63;
    int l1 = (w << 6) | h;
    size_t base = ((size_t)bl * 4) << 12;
    size_t i0 = (base + pg) << 7;
    size_t i1 = (base + 4096 + l1) << 7;
    size_t i2 = (base + 2 * 4096 + (4095 - pg)) << 7;
    size_t i3 = (base + 3 * 4096 + (4095 - l1)) << 7;
    float xx0 = xxc[(pp << 7) + lane], xx1 = xxc[(pp << 7) + 64 + lane];
    float y0 = ys[i0 + lane] + ys[i1 + lane] + ys[i2 + lane] + ys[i3 + lane] + xx0 * ds0;
    float y1 = ys[i0 + 64 + lane] + ys[i1 + 64 + lane] + ys[i2 + 64 + lane] + ys[i3 + 64 + lane] + xx1 * ds1;
    float s = wred64(y0 + y1);
    float s2 = wred64(y0 * y0 + y1 * y1);
    float m = s * (1.f / 128), var = s2 * (1.f / 128) - m * m;
    float rstd = rsqrtf(var + 1e-5f);
    float z0 = z[(pp << 7) + lane], z1 = z[(pp << 7) + 64 + lane];
    gb[lane][p] = ((y0 - m) * rstd * og0 + ob0) * silu(z0);
    gb[64 + lane][p] = ((y1 - m) * rstd * og1 + ob1) * silu(z1);
  }
  __syncthreads();
  int p0 = wv << 2;
  float4v acc = {0.f, 0.f, 0.f, 0.f};
  for (int c = 0; c < 128; ++c) {
    float w = opwt[(c << 6) + lane];
    acc += w * (*(const float4v*)&gb[c][p0]);
  }
  float accs[4];
  *(float4v*)&accs[0] = acc;
#pragma unroll
  for (int j = 0; j < 4; ++j) {
    size_t pp = pi0 + p0 + j;
    x1[pp * 64 + lane] = xres[pp * 64 + lane] + accs[j];
  }
}

// ln2 -> fc1 -> gelu(tanh) -> fc2 -> residual; 16 pos/block; wt[c][oc]
__global__ __launch_bounds__(256) void mlp_kernel(const float* __restrict__ x1,
                                                  const float* __restrict__ g2,
                                                  const float* __restrict__ b2,
                                                  const float* __restrict__ w1t,
                                                  const float* __restrict__ bb1,
                                                  const float* __restrict__ w2t,
                                                  const float* __restrict__ bb2,
                                                  float* __restrict__ x2) {
  int wv = threadIdx.x >> 6, lane = threadIdx.x & 63;
  size_t pi0 = (size_t)blockIdx.x << 4;
  __shared__ float xb[64][16], tb[64][16];
  float gv = g2[lane], bv = b2[lane];
  float xsave[4];
#pragma unroll
  for (int j = 0; j < 4; ++j) {
    int p = (wv << 2) + j;
    float xv = x1[(pi0 + p) * 64 + lane];
    xsave[j] = xv;
    float s = wred64(xv), s2 = wred64(xv * xv);
    float m = s * (1.f / 64), var = s2 * (1.f / 64) - m * m;
    float rstd = rsqrtf(var + 1e-5f);
    xb[lane][p] = (xv - m) * rstd * gv + bv;
  }
  __syncthreads();
  int p0 = wv << 2;
  float bb1v = bb1[lane];
  float4v acc = {bb1v, bb1v, bb1v, bb1v};
  for (int c = 0; c < 64; ++c) {
    float w = w1t[(c << 6) + lane];
    acc += w * (*(const float4v*)&xb[c][p0]);
  }
  float us[4];
  *(float4v*)&us[0] = acc;
#pragma unroll
  for (int j = 0; j < 4; ++j) {
    float u = us[j];
    float tt = tanhf(0.7978845608028654f * (u + 0.044715f * u * u * u));
    tb[lane][p0 + j] = 0.5f * u * (1.f + tt);
  }
  __syncthreads();
  float bb2v = bb2[lane];
  float4v acc2 = {bb2v, bb2v, bb2v, bb2v};
  for (int c = 0; c < 64; ++c) {
    float w = w2t[(c << 6) + lane];
    acc2 += w * (*(const float4v*)&tb[c][p0]);
  }
  float o2[4];
  *(float4v*)&o2[0] = acc2;
#pragma unroll
  for (int j = 0; j < 4; ++j)
    x2[(pi0 + p0 + j) * 64 + lane] = xsave[j] + o2[j];
}

// NHWC (bl,p,c) -> NCHW (bl,c,p) tiled transpose into d_out
__global__ __launch_bounds__(256) void transpose_out_kernel(const float* __restrict__ x2,
                                                            float* __restrict__ out) {
  int bi = blockIdx.x;
  int pt = bi & 127;
  int ct = (bi >> 7) & 1;
  int bl = bi >> 8;
  __shared__ float lds[32][33];
  int t = threadIdx.x;
  int j = t & 31, i0 = t >> 5;
  int p0 = pt << 5, c0 = ct << 5;
#pragma unroll
  for (int q = 0; q < 4; ++q) {
    int i = i0 + (q << 3);
    lds[i][j] = x2[((size_t)bl * NHW + p0 + i) * 64 + c0 + j];
  }
  __syncthreads();
#pragma unroll
  for (int q = 0; q < 4; ++q) {
    int i = i0 + (q << 3);
    out[((size_t)bl * 64 + c0 + i) * (size_t)NHW + p0 + j] = lds[j][i];
  }
}

extern "C" void kernel_launch(void* const* d_in, const int* in_sizes, int n_in,
                              void* d_out, int out_size, void* d_ws, size_t ws_size,
                              hipStream_t stream) {
  const float* img  = (const float*)d_in[0];
  const float* dz   = (const float*)d_in[1];
  const float* sg   = (const float*)d_in[2];
  const float* gn1g = (const float*)d_in[3];
  const float* gn1b = (const float*)d_in[4];
  const float* c1w  = (const float*)d_in[5];
  const float* c1b  = (const float*)d_in[6];
  const float* gn2g = (const float*)d_in[7];
  const float* gn2b = (const float*)d_in[8];
  const float* c2w  = (const float*)d_in[9];
  const float* c2b  = (const float*)d_in[10];
  const float* skw  = (const float*)d_in[11];
  const float* skb  = (const float*)d_in[12];
  const float* ln1g = (const float*)d_in[13];
  const float* ln1b = (const float*)d_in[14];
  const float* ln2g = (const float*)d_in[15];
  const float* ln2b = (const float*)d_in[16];
  const float* ipw  = (const float*)d_in[17];
  const float* dww  = (const float*)d_in[18];
  const float* dwb  = (const float*)d_in[19];
  const float* xpw  = (const float*)d_in[20];
  const float* dtw  = (const float*)d_in[21];
  const float* dtb  = (const float*)d_in[22];
  const float* Alog = (const float*)d_in[23];
  const float* Dsp  = (const float*)d_in[24];
  const float* ong  = (const float*)d_in[25];
  const float* onb  = (const float*)d_in[26];
  const float* opw  = (const float*)d_in[27];
  const float* f1w  = (const float*)d_in[28];
  const float* f1b  = (const float*)d_in[29];
  const float* f2w  = (const float*)d_in[30];
  const float* f2b  = (const float*)d_in[31];

  float* out = (float*)d_out;
  float* ws = (float*)d_ws;
  if (ws_size < F_TOTAL * sizeof(float)) return;

  float* xcat  = ws + F_XCAT;
  float* h1    = ws + F_H1;
  float* h2    = ws + F_H2;
  float* xres  = ws + F_XRES;
  float* xxin  = ws + F_XXIN;
  float* zbuf  = ws + F_Z;
  float* xxc   = ws + F_XXC;
  float* xdbl  = ws + F_XDBL;
  float* ysb   = ws + F_YS;
  float* x1    = ws + F_X1;
  float* x2    = ws + F_X2;
  float* stats = ws + F_STATS;
  ushortT* act1b = (ushortT*)(ws + F_ACT1);
  ushortT* act2b = (ushortT*)(ws + F_ACT2);
  // stats partials + conv weight packs live in X2 region (dead until mlp)
  double* part  = (double*)(ws + F_X2);              // 768 floats
  ushortT* wb1  = (ushortT*)(ws + F_X2 + 1024);      // 110592 ushorts
  ushortT* wb2  = wb1 + 110592;                      // 36864 ushorts
  // scan chunk arrays: H + sdt in YS (ys overwrites in pass3); HS in XCAT span
  float* chunkH   = ws + F_YS;                       // 6,291,456
  float* chunkSdt = ws + F_YS + 6291456;             // 393,216
  float* chunkHS  = ws + F_XCAT;                     // 6,291,456 (XCAT+ACT1, dead after inproj)
  // transposed small-GEMM weights
  float* wt_sk = ws + F_ACT1;                        // dead after skip
  float* wt_ip = ws + F_XCAT;                        // dead after inproj
  float* wt_op = ws + F_XXIN;                        // XXIN dead after dwconv
  float* wt_f1 = ws + F_XXIN + 8192;
  float* wt_f2 = ws + F_XXIN + 12288;

  // conv weight prepacks (no deps)
  wprep_kernel<<<432, 256, 0, stream>>>(c1w, wb1, NC3, 6);
  wprep_kernel<<<144, 256, 0, stream>>>(c2w, wb2, NC, 2);
  // stage 0: instance-norm stats
  stats1_kernel<<<NBL * 32, 256, 0, stream>>>(img, NC * NHW, part);
  stats2_kernel<<<NBL, 64, 0, stream>>>(part, NC * NHW, stats + 0, stats + 8);
  build_xcat_kernel<<<18432, 256, 0, stream>>>(img, dz, sg, stats, xcat);
  // gn1 + silu -> NHWC bf16
  stats1_kernel<<<NBL * 32, 256, 0, stream>>>(xcat, NC3 * NHW, part);
  stats2_kernel<<<NBL, 64, 0, stream>>>(part, NC3 * NHW, stats + 16, stats + 24);
  gnsilu_t_kernel<NC3><<<NBL * 64, 256, 0, stream>>>(xcat, gn1g, gn1b, stats + 16, act1b);
  conv_mfma_kernel<NC3><<<NBL * 64 * 2, 256, 0, stream>>>(act1b, wb1, c1b, h1);
  wtrans_kernel<<<48, 256, 0, stream>>>(skw, wt_sk, 64, 192);
  // gn2 + silu -> NHWC bf16
  stats1_kernel<<<NBL * 32, 256, 0, stream>>>(h1, NC * NHW, part);
  stats2_kernel<<<NBL, 64, 0, stream>>>(part, NC * NHW, stats + 32, stats + 40);
  gnsilu_t_kernel<NC><<<NBL * 64, 256, 0, stream>>>(h1, gn2g, gn2b, stats + 32, act2b);
  conv_mfma_kernel<NC><<<NBL * 64 * 2, 256, 0, stream>>>(act2b, wb2, c2b, h2);
  // skip 1x1 + residual + NHWC transpose
  skip_kernel<<<NBL * 64, 256, 0, stream>>>(xcat, h2, wt_sk, skb, xres);
  wtrans_kernel<<<64, 256, 0, stream>>>(ipw, wt_ip, 256, 64);
  // SS2D
  inproj_kernel<<<1536, 256, 0, stream>>>(xres, ln1g, ln1b, wt_ip, xxin, zbuf);
  dwconv_kernel<<<12288, 256, 0, stream>>>(xxin, dww, dwb, xxc);
  wtrans_kernel<<<32, 256, 0, stream>>>(opw, wt_op, 64, 128);
  wtrans_kernel<<<16, 256, 0, stream>>>(f1w, wt_f1, 64, 64);
  wtrans_kernel<<<16, 256, 0, stream>>>(f2w, wt_f2, 64, 64);
  xdbl_kernel<<<NBL * 2 * 64, 256, 0, stream>>>(xxc, xpw, xdbl);
  // chunked scan (128 chunks of 32); P compressed to sdt
  scan_pass1_kernel<<<24 * NCH, 128, 0, stream>>>(xdbl, xxc, dtw, dtb, Alog, chunkSdt, chunkH);
  scan_pass2_kernel<<<192, 256, 0, stream>>>(chunkSdt, chunkH, Alog, chunkHS);
  scan_pass3_kernel<<<24 * NCH, 128, 0, stream>>>(xdbl, xxc, dtw, dtb, Alog, chunkHS, ysb);
  // fused combine + out_norm + gate + out_proj + residual
  outproj_kernel<<<1536, 256, 0, stream>>>(ysb, xxc, Dsp, zbuf, ong, onb, wt_op, xres, x1);
  // MLP + residual
  mlp_kernel<<<1536, 256, 0, stream>>>(x1, ln2g, ln2b, wt_f1, f1b, wt_f2, f2b, x2);
  // final transpose to NCHW output
  transpose_out_kernel<<<NBL * 256, 256, 0, stream>>>(x2, out);
}

// Round 12
// 343.945 us; speedup vs baseline: 1.0433x; 1.0433x over previous
//
#include <hip/hip_runtime.h>
#include <hip/hip_bf16.h>

typedef unsigned short ushortT;
typedef short short8v __attribute__((ext_vector_type(8)));
typedef float float4v __attribute__((ext_vector_type(4)));

// Problem constants
#define NBL 6      // B*LEN
#define NC 64
#define NC3 192
#define NHW 4096   // 64*64
#define NDI 128
#define NNS 16
#define NDR 4
#define NK 4
#define NL 4096
#define NCH 128    // scan chunks
#define SCLEN 32   // chunk length
#define NSTATE 49152  // 24 bk * 128 d * 16 n

// workspace offsets in floats
static const size_t F_XCAT  = 0;          // 4,718,592 (wt_ip after skip; chunkHS16 during scan)
static const size_t F_ACT1  = 4718592;    // act1b bf16 NHWC; wt_sk after conv1
static const size_t F_H1    = 9437184;    // 1,572,864
static const size_t F_ACT2  = 11010048;   // act2b bf16 NHWC
static const size_t F_H2    = 12582912;   // 1,572,864
static const size_t F_XRES  = 14155776;   // 1,572,864
static const size_t F_XXIN  = 15728640;   // 3,145,728 (wt_op/f1/f2 after dwconv)
static const size_t F_Z     = 18874368;   // 3,145,728
static const size_t F_XXC   = 22020096;   // 3,145,728
static const size_t F_XDBL  = 25165824;   // 3,538,944
static const size_t F_YS    = 28704768;   // 12,582,912: ys-bf16 [0,6.29M) | chunkH16 [6.29M,9.44M) | sdt
static const size_t F_X1    = 44433408;   // 1,572,864
static const size_t F_X2    = 46006272;   // 1,572,864 (stats partials + conv wpacks)
static const size_t F_STATS = 47579136;   // 48
static const size_t F_TOTAL = 47579184;   // floats (~190.3 MB)

__device__ __forceinline__ float wred64(float v) {
#pragma unroll
  for (int m = 32; m; m >>= 1) v += __shfl_xor(v, m, 64);
  return v;
}

__device__ __forceinline__ float silu(float v) {
  return v / (1.f + __expf(-v));
}

__device__ __forceinline__ ushortT f2bf(float f) {
  unsigned int u = __builtin_bit_cast(unsigned int, f);
  unsigned int r = (u + 0x7FFFu + ((u >> 16) & 1u)) >> 16;
  return (ushortT)r;
}

__device__ __forceinline__ float bf2f(ushortT u) {
  return __builtin_bit_cast(float, (unsigned int)u << 16);
}

__device__ __forceinline__ int map_pos(int k, int l) {
  if (k == 0) return l;
  if (k == 1) return ((l & 63) << 6) | (l >> 6);
  if (k == 2) return 4095 - l;
  int lp = 4095 - l;
  return ((lp & 63) << 6) | (lp >> 6);
}

// softplus via hw exp2/log2
__device__ __forceinline__ float softplus_fast(float a) {
  float t = exp2f(a * 1.44269504f);
  float r = 0.69314718f * __log2f(1.f + t);
  return (a > 20.f) ? a : r;
}

// powers E^1..E^16 via mul tree (for geometric A: a_n = (n+1)*a_1)
__device__ __forceinline__ void pow_tree(float E1, float4v& e0, float4v& e1,
                                         float4v& e2, float4v& e3) {
  float E2 = E1 * E1, E3 = E2 * E1, E4 = E2 * E2;
  float E5 = E4 * E1, E6 = E4 * E2, E7 = E4 * E3, E8 = E4 * E4;
  e0[0] = E1; e0[1] = E2; e0[2] = E3; e0[3] = E4;
  e1[0] = E5; e1[1] = E6; e1[2] = E7; e1[3] = E8;
  e2[0] = E8 * E1; e2[1] = E8 * E2; e2[2] = E8 * E3; e2[3] = E8 * E4;
  e3[0] = E8 * E5; e3[1] = E8 * E6; e3[2] = E8 * E7; e3[3] = E8 * E8;
}

// generic weight transpose: dst[c*O + o] = src[o*C + c]
__global__ __launch_bounds__(256) void wtrans_kernel(const float* __restrict__ src,
                                                     float* __restrict__ dst, int O, int C) {
  int id = blockIdx.x * 256 + threadIdx.x;
  if (id >= O * C) return;
  int c = id / O, o = id % O;
  dst[id] = src[o * C + c];
}

// ---- two-stage per-sample mean/rstd (f64 accumulate) ----
__global__ __launch_bounds__(256) void stats1_kernel(const float* __restrict__ in, int n,
                                                     double* __restrict__ part) {
  int bi = blockIdx.x;
  int s = bi >> 5, j = bi & 31;
  int slice = n >> 5;
  const float4* p = (const float4*)(in + (size_t)s * n + (size_t)j * slice);
  int n4 = slice >> 2;
  double dsum = 0.0, dsq = 0.0;
  for (int i = threadIdx.x; i < n4; i += 256) {
    float4 v = p[i];
    dsum += (double)((v.x + v.y) + (v.z + v.w));
    dsq += (double)v.x * v.x + (double)v.y * v.y + (double)v.z * v.z + (double)v.w * v.w;
  }
  __shared__ double s1[256], s2[256];
  s1[threadIdx.x] = dsum; s2[threadIdx.x] = dsq;
  __syncthreads();
  for (int off = 128; off; off >>= 1) {
    if (threadIdx.x < off) { s1[threadIdx.x] += s1[threadIdx.x + off]; s2[threadIdx.x] += s2[threadIdx.x + off]; }
    __syncthreads();
  }
  if (threadIdx.x == 0) { part[2 * bi] = s1[0]; part[2 * bi + 1] = s2[0]; }
}

__global__ __launch_bounds__(64) void stats2_kernel(const double* __restrict__ part, int n,
                                                    float* __restrict__ mean_out,
                                                    float* __restrict__ rstd_out) {
  int s = blockIdx.x;
  int lane = threadIdx.x;
  double sum = 0.0, sq = 0.0;
  if (lane < 32) { sum = part[2 * (s * 32 + lane)]; sq = part[2 * (s * 32 + lane) + 1]; }
#pragma unroll
  for (int m = 16; m; m >>= 1) { sum += __shfl_xor(sum, m, 64); sq += __shfl_xor(sq, m, 64); }
  if (lane == 0) {
    double mean = sum / n;
    double var = sq / n - mean * mean;
    mean_out[s] = (float)mean;
    rstd_out[s] = (float)(1.0 / sqrt(var + 1e-5));
  }
}

// x_cat[bl][ch][p]: ch<64 dz, 64..127 instance-normed img, 128..191 sigma
__global__ __launch_bounds__(256) void build_xcat_kernel(const float* __restrict__ img,
                                                         const float* __restrict__ dz,
                                                         const float* __restrict__ sg,
                                                         const float* __restrict__ stats,
                                                         float* __restrict__ xcat) {
  size_t gid = (size_t)blockIdx.x * 256 + threadIdx.x;
  int p = gid & 4095;
  size_t r = gid >> 12;
  int ch = (int)(r % NC3);
  int bl = (int)(r / NC3);
  int b = bl / 3;
  float v;
  if (ch < 64) {
    v = dz[((size_t)b * NC + ch) * NHW + p];
  } else if (ch < 128) {
    float m = stats[bl], rs = stats[8 + bl];
    v = (img[((size_t)bl * NC + (ch - 64)) * NHW + p] - m) * rs;
  } else {
    v = sg[((size_t)b * NC + (ch - 128)) * NHW + p];
  }
  xcat[gid] = v;
}

// GN + SiLU + NCHW->NHWC transpose + f32->bf16. grid NBL*64, block 256.
template <int CCH>
__global__ __launch_bounds__(256) void gnsilu_t_kernel(const float* __restrict__ in,
                                                       const float* __restrict__ g,
                                                       const float* __restrict__ b,
                                                       const float* __restrict__ stats,
                                                       ushortT* __restrict__ outb) {
  int bi = blockIdx.x;
  int bl = bi >> 6, h = bi & 63;
  __shared__ ushortT tile[CCH][66];
  float m = stats[bl], rs = stats[8 + bl];
  int t = threadIdx.x;
  for (int idx = t; idx < CCH * 64; idx += 256) {
    int ch = idx >> 6, w = idx & 63;
    float v = in[(((size_t)bl * CCH + ch) << 12) + (h << 6) + w];
    v = (v - m) * rs * g[ch] + b[ch];
    v = silu(v);
    tile[ch][w] = f2bf(v);
  }
  __syncthreads();
  constexpr int C8 = CCH / 8;
  for (int idx = t; idx < 64 * C8; idx += 256) {
    int w = idx / C8, c8 = idx % C8;
    short8v v;
#pragma unroll
    for (int j = 0; j < 8; ++j) v[j] = (short)tile[c8 * 8 + j][w];
    *(short8v*)&outb[(size_t)(bl * 4096 + h * 64 + w) * CCH + c8 * 8] = v;
  }
}

// Pre-pack conv weights into per-lane MFMA B-fragments (bf16).
__global__ __launch_bounds__(256) void wprep_kernel(const float* __restrict__ w,
                                                    ushortT* __restrict__ out,
                                                    int CIN, int KT) {
  int id = blockIdx.x * 256 + threadIdx.x;
  int j = id & 7;
  int lane = (id >> 3) & 63;
  int nt = (id >> 9) & 3;
  int rest = id >> 11;
  int kt = rest % KT;
  int tap = rest / KT;
  int oc = nt * 16 + (lane & 15);
  int ic = kt * 32 + ((lane >> 4) << 3) + j;
  int r = tap / 3, s = tap % 3;
  out[id] = f2bf(w[(((size_t)oc * CIN + ic) * 3 + r) * 3 + s]);
}

// Implicit-GEMM 3x3 SAME conv via bf16 MFMA, f32 accumulate.
template <int CIN>
__global__ __launch_bounds__(256) void conv_mfma_kernel(const ushortT* __restrict__ actb,
                                                        const ushortT* __restrict__ wb,
                                                        const float* __restrict__ bias,
                                                        float* __restrict__ out) {
  constexpr int KT = CIN / 32;
  constexpr int STRIDE = CIN + 8;
  constexpr int C8 = CIN / 8;
  int bi = blockIdx.x;
  int nh = bi & 1;
  int h = (bi >> 1) & 63;
  int bl = bi >> 7;
  int t = threadIdx.x;
  int wv = t >> 6, lane = t & 63;
  __shared__ ushortT lds[66 * STRIDE];
  float4v acc0 = {0.f, 0.f, 0.f, 0.f};
  float4v acc1 = {0.f, 0.f, 0.f, 0.f};
  int lrow = lane & 15;
  int lk = (lane >> 4) << 3;
  for (int dy = 0; dy < 3; ++dy) {
    int hh = h + dy - 1;
    bool valid = (hh >= 0) && (hh < 64);
    int hc = valid ? hh : 0;
    if (dy) __syncthreads();
    const ushortT* src = actb + (size_t)(bl * 4096 + hc * 64) * CIN;
    for (int idx = t; idx < 64 * C8; idx += 256) {
      int w = idx / C8, c8 = idx % C8;
      short8v v = {0, 0, 0, 0, 0, 0, 0, 0};
      if (valid) v = *(const short8v*)&src[(size_t)w * CIN + c8 * 8];
      *(short8v*)&lds[(w + 1) * STRIDE + c8 * 8] = v;
    }
    if (t < 2 * C8) {
      int which = t / C8, c8 = t % C8;
      short8v z = {0, 0, 0, 0, 0, 0, 0, 0};
      *(short8v*)&lds[(which ? 65 : 0) * STRIDE + c8 * 8] = z;
    }
    __syncthreads();
    for (int dx = 0; dx < 3; ++dx) {
      int tap = dy * 3 + dx;
      int wl = (wv << 4) + lrow + dx;
#pragma unroll
      for (int kt = 0; kt < KT; ++kt) {
        short8v a = *(const short8v*)&lds[wl * STRIDE + kt * 32 + lk];
        const ushortT* wp = wb + ((size_t)(((tap * KT + kt) * 4 + (nh << 1)) * 64 + lane) << 3);
        short8v b0 = *(const short8v*)&wp[0];
        short8v b1 = *(const short8v*)&wp[512];
        acc0 = __builtin_amdgcn_mfma_f32_16x16x32_bf16(a, b0, acc0, 0, 0, 0);
        acc1 = __builtin_amdgcn_mfma_f32_16x16x32_bf16(a, b1, acc1, 0, 0, 0);
      }
    }
  }
  int oc0 = (nh << 5) + lrow;
  int oc1 = oc0 + 16;
  int w0 = (wv << 4) + ((lane >> 4) << 2);
  float bv0 = bias[oc0], bv1 = bias[oc1];
  float4 o0 = make_float4(acc0[0] + bv0, acc0[1] + bv0, acc0[2] + bv0, acc0[3] + bv0);
  float4 o1 = make_float4(acc1[0] + bv1, acc1[1] + bv1, acc1[2] + bv1, acc1[3] + bv1);
  *(float4*)&out[(((size_t)bl * 64 + oc0) << 12) + (h << 6) + w0] = o0;
  *(float4*)&out[(((size_t)bl * 64 + oc1) << 12) + (h << 6) + w0] = o1;
}

// x_res[bl][p][oc] = h2[bl][oc][p] + 1x1skip(xcat)[oc] + skb[oc]   (NHWC out)
__global__ __launch_bounds__(256) void skip_kernel(const float* __restrict__ xcat,
                                                   const float* __restrict__ h2,
                                                   const float* __restrict__ skwt,
                                                   const float* __restrict__ skb,
                                                   float* __restrict__ xres) {
  int bi = blockIdx.x;
  int bl = bi >> 6, h = bi & 63;
  int t = threadIdx.x;
  int oc = t & 63, w0 = (t >> 6) << 4;
  __shared__ float lds[64][64];
  float acc[16];
#pragma unroll
  for (int i = 0; i < 16; ++i) acc[i] = 0.f;
  for (int cc = 0; cc < 3; ++cc) {
    __syncthreads();
    for (int idx = t; idx < 4096; idx += 256) {
      int ch = idx >> 6, w = idx & 63;
      lds[ch][w] = xcat[(((size_t)bl * NC3 + cc * 64 + ch) << 12) + (h << 6) + w];
    }
    __syncthreads();
    for (int ch = 0; ch < 64; ++ch) {
      float wv = skwt[((cc << 6) + ch) * 64 + oc];
#pragma unroll
      for (int i = 0; i < 16; ++i) acc[i] += wv * lds[ch][w0 + i];
    }
  }
  float bv = skb[oc];
  int p0 = (h << 6) + w0;
#pragma unroll
  for (int i = 0; i < 16; ++i) {
    float hv = h2[(((size_t)bl * 64 + oc) << 12) + p0 + i];
    xres[((size_t)bl * NHW + p0 + i) * 64 + oc] = acc[i] + bv + hv;
  }
}

// LN(ln1) + 64->256 proj; 16 positions per block; wt[c(64)][oc(256)]. grid 1536.
__global__ __launch_bounds__(256) void inproj_kernel(const float* __restrict__ xres,
                                                     const float* __restrict__ g,
                                                     const float* __restrict__ b,
                                                     const float* __restrict__ wt,
                                                     float* __restrict__ xxin,
                                                     float* __restrict__ z) {
  int wv = threadIdx.x >> 6, lane = threadIdx.x & 63;
  size_t pi0 = (size_t)blockIdx.x << 4;
  __shared__ float xb[64][16];
  float gv = g[lane], bv = b[lane];
#pragma unroll
  for (int j = 0; j < 4; ++j) {
    int p = (wv << 2) + j;
    float x = xres[(pi0 + p) * 64 + lane];
    float s = wred64(x);
    float s2 = wred64(x * x);
    float m = s * (1.f / 64), var = s2 * (1.f / 64) - m * m;
    float rstd = rsqrtf(var + 1e-5f);
    xb[lane][p] = (x - m) * rstd * gv + bv;
  }
  __syncthreads();
  int oc = (wv << 6) + lane;
  float4v a0 = {0.f, 0.f, 0.f, 0.f}, a1 = a0, a2 = a0, a3 = a0;
  for (int c = 0; c < 64; ++c) {
    float w = wt[(c << 8) + oc];
    const float4v* xr = (const float4v*)&xb[c][0];
    a0 += w * xr[0];
    a1 += w * xr[1];
    a2 += w * xr[2];
    a3 += w * xr[3];
  }
  float acc[16];
  *(float4v*)&acc[0] = a0;
  *(float4v*)&acc[4] = a1;
  *(float4v*)&acc[8] = a2;
  *(float4v*)&acc[12] = a3;
  float* dst = (oc < 128) ? xxin : z;
  int oco = (oc < 128) ? oc : (oc - 128);
#pragma unroll
  for (int p = 0; p < 16; ++p) dst[((pi0 + p) << 7) + oco] = acc[p];
}

// depthwise 3x3 SAME + bias + silu on NHWC [bl][p][128]
__global__ __launch_bounds__(256) void dwconv_kernel(const float* __restrict__ xx,
                                                     const float* __restrict__ w,
                                                     const float* __restrict__ b,
                                                     float* __restrict__ out) {
  size_t gid = (size_t)blockIdx.x * 256 + threadIdx.x;
  int d = gid & 127;
  size_t pi = gid >> 7;
  int p = (int)(pi & 4095);
  int bl = (int)(pi >> 12);
  int h = p >> 6, wq = p & 63;
  float acc = b[d];
  const float* wr = w + d * 9;
#pragma unroll
  for (int dy = -1; dy <= 1; ++dy) {
    int hh = h + dy;
    if (hh < 0 || hh >= 64) continue;
#pragma unroll
    for (int dx = -1; dx <= 1; ++dx) {
      int ww = wq + dx;
      if (ww < 0 || ww >= 64) continue;
      acc += wr[(dy + 1) * 3 + (dx + 1)] * xx[(((size_t)bl << 12) + (hh << 6) + ww) * 128 + d];
    }
  }
  out[pi * 128 + d] = silu(acc);
}

// x_dbl via shared hw/wh tile; computes forward k and reversed k+2 per block.
__global__ __launch_bounds__(256) void xdbl_kernel(const float* __restrict__ xxc,
                                                   const float* __restrict__ xpw,
                                                   float* __restrict__ xdbl) {
  int bi = blockIdx.x;
  int lt = bi & 63;
  int korder = (bi >> 6) & 1;
  int bl = bi >> 7;
  int lbase = lt << 6;
  __shared__ float xs[64 * 128];
  int t = threadIdx.x;
#pragma unroll
  for (int it = 0; it < 8; ++it) {
    int idx = it * 256 + t;
    int i = idx >> 5, d4 = idx & 31;
    int l = lbase + i;
    int pos = korder ? (((l & 63) << 6) | (l >> 6)) : l;
    float4 v = *(const float4*)&xxc[((size_t)bl * NHW + pos) * 128 + (d4 << 2)];
    int slot = d4 ^ (i & 7);
    *(float4*)&xs[i * 128 + (slot << 2)] = v;
  }
  __syncthreads();
  int wv = __builtin_amdgcn_readfirstlane(t >> 6);
  int lane = t & 63;
  int k_w = korder + ((wv >= 2) ? 2 : 0);
  int c0 = (wv & 1) * 18;
  float acc[18];
#pragma unroll
  for (int j = 0; j < 18; ++j) acc[j] = 0.f;
  const float* wbase = xpw + (size_t)(k_w * 36 + c0) * 128;
  for (int d4 = 0; d4 < 32; ++d4) {
    int slot = d4 ^ (lane & 7);
    float4 x4 = *(const float4*)&xs[lane * 128 + (slot << 2)];
#pragma unroll
    for (int j = 0; j < 18; ++j) {
      float4 w4 = *(const float4*)&wbase[j * 128 + (d4 << 2)];
      acc[j] += w4.x * x4.x + w4.y * x4.y + w4.z * x4.z + w4.w * x4.w;
    }
  }
  int lout = (k_w < 2) ? (lbase + lane) : (4095 - lbase - lane);
  size_t obase = ((size_t)(bl * 4 + k_w) * 36 + c0) * (size_t)NL + lout;
#pragma unroll
  for (int j = 0; j < 18; ++j)
    xdbl[obase + (size_t)j * NL] = acc[j];
}

// ---- chunked selective scan ----
// Pass 1: local scan; H stored bf16, sdt scalar f32.
__global__ __launch_bounds__(128) void scan_pass1_kernel(const float* __restrict__ xdbl,
                                                         const float* __restrict__ xxc,
                                                         const float* __restrict__ dtw,
                                                         const float* __restrict__ dtb,
                                                         const float* __restrict__ Alog,
                                                         float* __restrict__ chunkSdt,
                                                         ushortT* __restrict__ chunkH16) {
  int bi = blockIdx.x;
  int chunk = bi & (NCH - 1);
  int bk = bi >> 7;
  int k = bk & 3, bl = bk >> 2;
  int d = threadIdx.x;
  float4 wv = *(const float4*)(dtw + (size_t)(((k << 7) + d) << 2));
  float bias = dtb[(k << 7) + d];
  const float* ar = Alog + (size_t)(((k << 7) + d) << 4);
  float a1v = -__expf(ar[0]) * 1.44269504f;
  bool geom = true;
#pragma unroll
  for (int n = 1; n < 16; ++n) {
    float an = -__expf(ar[n]) * 1.44269504f;
    geom = geom && (fabsf(an - (float)(n + 1) * a1v) <= 1e-3f * fabsf((float)(n + 1) * a1v) + 1e-6f);
  }
  __shared__ float xd[SCLEN][20];
  int l0 = chunk << 5;
  for (int idx = threadIdx.x; idx < 20 * SCLEN; idx += 128) {
    int c = idx >> 5, li = idx & 31;
    xd[li][c] = xdbl[((size_t)bk * 36 + c) * (size_t)NL + l0 + li];
  }
  __syncthreads();
  const float* uB = xxc + ((size_t)bl << 19) + d;
  float4v h0 = {0.f, 0.f, 0.f, 0.f}, h1 = h0, h2 = h0, h3 = h0;
  float sdt = 0.f;
  float u_nxt = uB[(size_t)map_pos(k, l0) << 7];
  if (geom) {
    for (int li = 0; li < SCLEN; ++li) {
      float u = u_nxt;
      int nl = (li < SCLEN - 1) ? (li + 1) : (SCLEN - 1);
      u_nxt = uB[(size_t)map_pos(k, l0 + nl) << 7];
      const float4v* row = (const float4v*)&xd[li][0];
      float4v q0 = row[0];
      float accq = bias + wv.x * q0[0] + wv.y * q0[1] + wv.z * q0[2] + wv.w * q0[3];
      float dt = softplus_fast(accq);
      float dtu = dt * u;
      sdt += dt;
      float4v b0 = row[1], b1 = row[2], b2 = row[3], b3 = row[4];
      float4v e0, e1, e2, e3;
      pow_tree(exp2f(a1v * dt), e0, e1, e2, e3);
      h0 = e0 * h0 + dtu * b0;
      h1 = e1 * h1 + dtu * b1;
      h2 = e2 * h2 + dtu * b2;
      h3 = e3 * h3 + dtu * b3;
    }
  } else {
    float4v a0v, a1q, a2q, a3q;
#pragma unroll
    for (int j = 0; j < 4; ++j) {
      a0v[j] = -__expf(ar[j]) * 1.44269504f;
      a1q[j] = -__expf(ar[4 + j]) * 1.44269504f;
      a2q[j] = -__expf(ar[8 + j]) * 1.44269504f;
      a3q[j] = -__expf(ar[12 + j]) * 1.44269504f;
    }
    for (int li = 0; li < SCLEN; ++li) {
      float u = u_nxt;
      int nl = (li < SCLEN - 1) ? (li + 1) : (SCLEN - 1);
      u_nxt = uB[(size_t)map_pos(k, l0 + nl) << 7];
      const float4v* row = (const float4v*)&xd[li][0];
      float4v q0 = row[0];
      float accq = bias + wv.x * q0[0] + wv.y * q0[1] + wv.z * q0[2] + wv.w * q0[3];
      float dt = softplus_fast(accq);
      float dtu = dt * u;
      sdt += dt;
      float4v b0 = row[1], b1 = row[2], b2 = row[3], b3 = row[4];
      float4v e0, e1, e2, e3;
#pragma unroll
      for (int j = 0; j < 4; ++j) {
        e0[j] = exp2f(a0v[j] * dt);
        e1[j] = exp2f(a1q[j] * dt);
        e2[j] = exp2f(a2q[j] * dt);
        e3[j] = exp2f(a3q[j] * dt);
      }
      h0 = e0 * h0 + dtu * b0;
      h1 = e1 * h1 + dtu * b1;
      h2 = e2 * h2 + dtu * b2;
      h3 = e3 * h3 + dtu * b3;
    }
  }
  size_t base = (size_t)chunk * NSTATE + (((size_t)bk << 7) + (size_t)d) * 16;
  chunkSdt[(size_t)chunk * 3072 + (bk << 7) + d] = sdt;
  short8v s0, s1;
#pragma unroll
  for (int j = 0; j < 4; ++j) {
    s0[j] = (short)f2bf(h0[j]);
    s0[4 + j] = (short)f2bf(h1[j]);
    s1[j] = (short)f2bf(h2[j]);
    s1[4 + j] = (short)f2bf(h3[j]);
  }
  *(short8v*)&chunkH16[base + 0] = s0;
  *(short8v*)&chunkH16[base + 8] = s1;
}

// Pass 2: per-state combine; P recomputed from sdt; H bf16 in, HS bf16 out.
__global__ __launch_bounds__(256) void scan_pass2_kernel(const float* __restrict__ chunkSdt,
                                                         const ushortT* __restrict__ chunkH16,
                                                         const float* __restrict__ Alog,
                                                         ushortT* __restrict__ chunkHS16) {
  size_t state = (size_t)blockIdx.x * 256 + threadIdx.x;  // < 49152
  float an = -__expf(Alog[state & 8191]) * 1.44269504f;
  int kd = (int)(state >> 4);
  float h = 0.f;
  for (int j = 0; j < NCH; ++j) {
    size_t idx = (size_t)j * NSTATE + state;
    chunkHS16[idx] = f2bf(h);
    float sdt = chunkSdt[(size_t)j * 3072 + kd];
    h = exp2f(an * sdt) * h + bf2f(chunkH16[idx]);
  }
}

__global__ __launch_bounds__(128) void scan_pass3_kernel(const float* __restrict__ xdbl,
                                                         const float* __restrict__ xxc,
                                                         const float* __restrict__ dtw,
                                                         const float* __restrict__ dtb,
                                                         const float* __restrict__ Alog,
                                                         const ushortT* __restrict__ chunkHS16,
                                                         ushortT* __restrict__ ys16) {
  int bi = blockIdx.x;
  int chunk = bi & (NCH - 1);
  int bk = bi >> 7;
  int k = bk & 3, bl = bk >> 2;
  int d = threadIdx.x;
  float4 wv = *(const float4*)(dtw + (size_t)(((k << 7) + d) << 2));
  float bias = dtb[(k << 7) + d];
  const float* ar = Alog + (size_t)(((k << 7) + d) << 4);
  float a1v = -__expf(ar[0]) * 1.44269504f;
  bool geom = true;
#pragma unroll
  for (int n = 1; n < 16; ++n) {
    float an = -__expf(ar[n]) * 1.44269504f;
    geom = geom && (fabsf(an - (float)(n + 1) * a1v) <= 1e-3f * fabsf((float)(n + 1) * a1v) + 1e-6f);
  }
  __shared__ float xd[SCLEN][36];
  int l0 = chunk << 5;
  for (int idx = threadIdx.x; idx < 36 * SCLEN; idx += 128) {
    int c = idx >> 5, li = idx & 31;
    xd[li][c] = xdbl[((size_t)bk * 36 + c) * (size_t)NL + l0 + li];
  }
  __syncthreads();
  const float* uB = xxc + ((size_t)bl << 19) + d;
  ushortT* yB = ys16 + ((size_t)bk << 19) + d;
  size_t base = (size_t)chunk * NSTATE + (((size_t)bk << 7) + (size_t)d) * 16;
  float4v h0, h1, h2, h3;
  {
    short8v s0 = *(const short8v*)&chunkHS16[base + 0];
    short8v s1 = *(const short8v*)&chunkHS16[base + 8];
#pragma unroll
    for (int j = 0; j < 4; ++j) {
      h0[j] = bf2f((ushortT)s0[j]);
      h1[j] = bf2f((ushortT)s0[4 + j]);
      h2[j] = bf2f((ushortT)s1[j]);
      h3[j] = bf2f((ushortT)s1[4 + j]);
    }
  }
  float u_nxt = uB[(size_t)map_pos(k, l0) << 7];
  if (geom) {
    for (int li = 0; li < SCLEN; ++li) {
      float u = u_nxt;
      int nl = (li < SCLEN - 1) ? (li + 1) : (SCLEN - 1);
      u_nxt = uB[(size_t)map_pos(k, l0 + nl) << 7];
      const float4v* row = (const float4v*)&xd[li][0];
      float4v q0 = row[0];
      float accq = bias + wv.x * q0[0] + wv.y * q0[1] + wv.z * q0[2] + wv.w * q0[3];
      float dt = softplus_fast(accq);
      float dtu = dt * u;
      float4v b0 = row[1], b1 = row[2], b2 = row[3], b3 = row[4];
      float4v c0 = row[5], c1 = row[6], c2 = row[7], c3 = row[8];
      float4v e0, e1, e2, e3;
      pow_tree(exp2f(a1v * dt), e0, e1, e2, e3);
      h0 = e0 * h0 + dtu * b0;
      h1 = e1 * h1 + dtu * b1;
      h2 = e2 * h2 + dtu * b2;
      h3 = e3 * h3 + dtu * b3;
      float4v sy = h0 * c0;
      sy += h1 * c1;
      sy += h2 * c2;
      sy += h3 * c3;
      yB[(size_t)(l0 + li) << 7] = f2bf((sy[0] + sy[1]) + (sy[2] + sy[3]));
    }
  } else {
    float4v a0v, a1q, a2q, a3q;
#pragma unroll
    for (int j = 0; j < 4; ++j) {
      a0v[j] = -__expf(ar[j]) * 1.44269504f;
      a1q[j] = -__expf(ar[4 + j]) * 1.44269504f;
      a2q[j] = -__expf(ar[8 + j]) * 1.44269504f;
      a3q[j] = -__expf(ar[12 + j]) * 1.44269504f;
    }
    for (int li = 0; li < SCLEN; ++li) {
      float u = u_nxt;
      int nl = (li < SCLEN - 1) ? (li + 1) : (SCLEN - 1);
      u_nxt = uB[(size_t)map_pos(k, l0 + nl) << 7];
      const float4v* row = (const float4v*)&xd[li][0];
      float4v q0 = row[0];
      float accq = bias + wv.x * q0[0] + wv.y * q0[1] + wv.z * q0[2] + wv.w * q0[3];
      float dt = softplus_fast(accq);
      float dtu = dt * u;
      float4v b0 = row[1], b1 = row[2], b2 = row[3], b3 = row[4];
      float4v c0 = row[5], c1 = row[6], c2 = row[7], c3 = row[8];
      float4v e0, e1, e2, e3;
#pragma unroll
      for (int j = 0; j < 4; ++j) {
        e0[j] = exp2f(a0v[j] * dt);
        e1[j] = exp2f(a1q[j] * dt);
        e2[j] = exp2f(a2q[j] * dt);
        e3[j] = exp2f(a3q[j] * dt);
      }
      h0 = e0 * h0 + dtu * b0;
      h1 = e1 * h1 + dtu * b1;
      h2 = e2 * h2 + dtu * b2;
      h3 = e3 * h3 + dtu * b3;
      float4v sy = h0 * c0;
      sy += h1 * c1;
      sy += h2 * c2;
      sy += h3 * c3;
      yB[(size_t)(l0 + li) << 7] = f2bf((sy[0] + sy[1]) + (sy[2] + sy[3]));
    }
  }
}

// Fused: 4-direction combine (bf16 ys) + D*xxc + out_norm LN -> *silu(z) -> out_proj -> +x_res
__global__ __launch_bounds__(256) void outproj_kernel(const ushortT* __restrict__ ys16,
                                                      const float* __restrict__ xxc,
                                                      const float* __restrict__ Ds,
                                                      const float* __restrict__ z,
                                                      const float* __restrict__ ong,
                                                      const float* __restrict__ onb,
                                                      const float* __restrict__ opwt,
                                                      const float* __restrict__ xres,
                                                      float* __restrict__ x1) {
  int wv = threadIdx.x >> 6, lane = threadIdx.x & 63;
  size_t pi0 = (size_t)blockIdx.x << 4;
  __shared__ float gb[128][16];
  float og0 = ong[lane], ob0 = onb[lane];
  float og1 = ong[64 + lane], ob1 = onb[64 + lane];
  float ds0 = Ds[lane] + Ds[128 + lane] + Ds[256 + lane] + Ds[384 + lane];
  float ds1 = Ds[64 + lane] + Ds[192 + lane] + Ds[320 + lane] + Ds[448 + lane];
#pragma unroll
  for (int j = 0; j < 4; ++j) {
    int p = (wv << 2) + j;
    size_t pp = pi0 + p;
    int bl = (int)(pp >> 12);
    int pg = (int)(pp & 4095);
    int h = pg >> 6, w = pg & 63;
    int l1 = (w << 6) | h;
    size_t base = ((size_t)bl * 4) << 12;
    size_t i0 = (base + pg) << 7;
    size_t i1 = (base + 4096 + l1) << 7;
    size_t i2 = (base + 2 * 4096 + (4095 - pg)) << 7;
    size_t i3 = (base + 3 * 4096 + (4095 - l1)) << 7;
    float xx0 = xxc[(pp << 7) + lane], xx1 = xxc[(pp << 7) + 64 + lane];
    float y0 = bf2f(ys16[i0 + lane]) + bf2f(ys16[i1 + lane]) + bf2f(ys16[i2 + lane]) +
               bf2f(ys16[i3 + lane]) + xx0 * ds0;
    float y1 = bf2f(ys16[i0 + 64 + lane]) + bf2f(ys16[i1 + 64 + lane]) +
               bf2f(ys16[i2 + 64 + lane]) + bf2f(ys16[i3 + 64 + lane]) + xx1 * ds1;
    float s = wred64(y0 + y1);
    float s2 = wred64(y0 * y0 + y1 * y1);
    float m = s * (1.f / 128), var = s2 * (1.f / 128) - m * m;
    float rstd = rsqrtf(var + 1e-5f);
    float z0 = z[(pp << 7) + lane], z1 = z[(pp << 7) + 64 + lane];
    gb[lane][p] = ((y0 - m) * rstd * og0 + ob0) * silu(z0);
    gb[64 + lane][p] = ((y1 - m) * rstd * og1 + ob1) * silu(z1);
  }
  __syncthreads();
  int p0 = wv << 2;
  float4v acc = {0.f, 0.f, 0.f, 0.f};
  for (int c = 0; c < 128; ++c) {
    float w = opwt[(c << 6) + lane];
    acc += w * (*(const float4v*)&gb[c][p0]);
  }
  float accs[4];
  *(float4v*)&accs[0] = acc;
#pragma unroll
  for (int j = 0; j < 4; ++j) {
    size_t pp = pi0 + p0 + j;
    x1[pp * 64 + lane] = xres[pp * 64 + lane] + accs[j];
  }
}

// ln2 -> fc1 -> gelu(tanh) -> fc2 -> residual -> NCHW output (fused transpose)
__global__ __launch_bounds__(256) void mlp_kernel(const float* __restrict__ x1,
                                                  const float* __restrict__ g2,
                                                  const float* __restrict__ b2,
                                                  const float* __restrict__ w1t,
                                                  const float* __restrict__ bb1,
                                                  const float* __restrict__ w2t,
                                                  const float* __restrict__ bb2,
                                                  float* __restrict__ out) {
  int wv = threadIdx.x >> 6, lane = threadIdx.x & 63;
  size_t pi0 = (size_t)blockIdx.x << 4;
  __shared__ float xb[64][16], tb[64][16];
  __shared__ float ot[64][17];
  float gv = g2[lane], bv = b2[lane];
  float xsave[4];
#pragma unroll
  for (int j = 0; j < 4; ++j) {
    int p = (wv << 2) + j;
    float xv = x1[(pi0 + p) * 64 + lane];
    xsave[j] = xv;
    float s = wred64(xv), s2 = wred64(xv * xv);
    float m = s * (1.f / 64), var = s2 * (1.f / 64) - m * m;
    float rstd = rsqrtf(var + 1e-5f);
    xb[lane][p] = (xv - m) * rstd * gv + bv;
  }
  __syncthreads();
  int p0 = wv << 2;
  float bb1v = bb1[lane];
  float4v acc = {bb1v, bb1v, bb1v, bb1v};
  for (int c = 0; c < 64; ++c) {
    float w = w1t[(c << 6) + lane];
    acc += w * (*(const float4v*)&xb[c][p0]);
  }
  float us[4];
  *(float4v*)&us[0] = acc;
#pragma unroll
  for (int j = 0; j < 4; ++j) {
    float u = us[j];
    float tt = tanhf(0.7978845608028654f * (u + 0.044715f * u * u * u));
    tb[lane][p0 + j] = 0.5f * u * (1.f + tt);
  }
  __syncthreads();
  float bb2v = bb2[lane];
  float4v acc2 = {bb2v, bb2v, bb2v, bb2v};
  for (int c = 0; c < 64; ++c) {
    float w = w2t[(c << 6) + lane];
    acc2 += w * (*(const float4v*)&tb[c][p0]);
  }
  float o2[4];
  *(float4v*)&o2[0] = acc2;
#pragma unroll
  for (int j = 0; j < 4; ++j)
    ot[lane][p0 + j] = xsave[j] + o2[j];
  __syncthreads();
  // write NCHW: out[bl][c][pg0..pg0+15]
  int bl = (int)(pi0 >> 12);
  int pg0 = (int)(pi0 & 4095);
  int t = threadIdx.x;
  int c = t >> 2, q = t & 3;
  float4 v = make_float4(ot[c][(q << 2) + 0], ot[c][(q << 2) + 1],
                         ot[c][(q << 2) + 2], ot[c][(q << 2) + 3]);
  *(float4*)&out[(((size_t)bl * 64 + c) << 12) + pg0 + (q << 2)] = v;
}

extern "C" void kernel_launch(void* const* d_in, const int* in_sizes, int n_in,
                              void* d_out, int out_size, void* d_ws, size_t ws_size,
                              hipStream_t stream) {
  const float* img  = (const float*)d_in[0];
  const float* dz   = (const float*)d_in[1];
  const float* sg   = (const float*)d_in[2];
  const float* gn1g = (const float*)d_in[3];
  const float* gn1b = (const float*)d_in[4];
  const float* c1w  = (const float*)d_in[5];
  const float* c1b  = (const float*)d_in[6];
  const float* gn2g = (const float*)d_in[7];
  const float* gn2b = (const float*)d_in[8];
  const float* c2w  = (const float*)d_in[9];
  const float* c2b  = (const float*)d_in[10];
  const float* skw  = (const float*)d_in[11];
  const float* skb  = (const float*)d_in[12];
  const float* ln1g = (const float*)d_in[13];
  const float* ln1b = (const float*)d_in[14];
  const float* ln2g = (const float*)d_in[15];
  const float* ln2b = (const float*)d_in[16];
  const float* ipw  = (const float*)d_in[17];
  const float* dww  = (const float*)d_in[18];
  const float* dwb  = (const float*)d_in[19];
  const float* xpw  = (const float*)d_in[20];
  const float* dtw  = (const float*)d_in[21];
  const float* dtb  = (const float*)d_in[22];
  const float* Alog = (const float*)d_in[23];
  const float* Dsp  = (const float*)d_in[24];
  const float* ong  = (const float*)d_in[25];
  const float* onb  = (const float*)d_in[26];
  const float* opw  = (const float*)d_in[27];
  const float* f1w  = (const float*)d_in[28];
  const float* f1b  = (const float*)d_in[29];
  const float* f2w  = (const float*)d_in[30];
  const float* f2b  = (const float*)d_in[31];

  float* out = (float*)d_out;
  float* ws = (float*)d_ws;
  if (ws_size < F_TOTAL * sizeof(float)) return;

  float* xcat  = ws + F_XCAT;
  float* h1    = ws + F_H1;
  float* h2    = ws + F_H2;
  float* xres  = ws + F_XRES;
  float* xxin  = ws + F_XXIN;
  float* zbuf  = ws + F_Z;
  float* xxc   = ws + F_XXC;
  float* xdbl  = ws + F_XDBL;
  float* x1    = ws + F_X1;
  float* stats = ws + F_STATS;
  ushortT* act1b = (ushortT*)(ws + F_ACT1);
  ushortT* act2b = (ushortT*)(ws + F_ACT2);
  // stats partials + conv weight packs live in X2 region (dead scratch)
  double* part  = (double*)(ws + F_X2);              // 768 floats
  ushortT* wb1  = (ushortT*)(ws + F_X2 + 1024);      // 110592 ushorts
  ushortT* wb2  = wb1 + 110592;                      // 36864 ushorts
  // scan arrays in YS region: ys bf16 | chunkH bf16 | sdt f32 (no overlap)
  ushortT* ys16     = (ushortT*)(ws + F_YS);               // 12.58M ushorts (6.29M floats)
  ushortT* chunkH16 = (ushortT*)(ws + F_YS + 6291456);     // 6.29M ushorts (3.15M floats)
  float*   chunkSdt = ws + F_YS + 6291456 + 3145728;       // 393,216 floats
  ushortT* chunkHS16 = (ushortT*)(ws + F_XCAT);            // 6.29M ushorts (XCAT dead after inproj)
  // transposed small-GEMM weights
  float* wt_sk = ws + F_ACT1;                        // dead after skip
  float* wt_ip = ws + F_XCAT;                        // dead after inproj
  float* wt_op = ws + F_XXIN;                        // XXIN dead after dwconv
  float* wt_f1 = ws + F_XXIN + 8192;
  float* wt_f2 = ws + F_XXIN + 12288;

  // conv weight prepacks (no deps)
  wprep_kernel<<<432, 256, 0, stream>>>(c1w, wb1, NC3, 6);
  wprep_kernel<<<144, 256, 0, stream>>>(c2w, wb2, NC, 2);
  // stage 0: instance-norm stats
  stats1_kernel<<<NBL * 32, 256, 0, stream>>>(img, NC * NHW, part);
  stats2_kernel<<<NBL, 64, 0, stream>>>(part, NC * NHW, stats + 0, stats + 8);
  build_xcat_kernel<<<18432, 256, 0, stream>>>(img, dz, sg, stats, xcat);
  // gn1 + silu -> NHWC bf16
  stats1_kernel<<<NBL * 32, 256, 0, stream>>>(xcat, NC3 * NHW, part);
  stats2_kernel<<<NBL, 64, 0, stream>>>(part, NC3 * NHW, stats + 16, stats + 24);
  gnsilu_t_kernel<NC3><<<NBL * 64, 256, 0, stream>>>(xcat, gn1g, gn1b, stats + 16, act1b);
  conv_mfma_kernel<NC3><<<NBL * 64 * 2, 256, 0, stream>>>(act1b, wb1, c1b, h1);
  wtrans_kernel<<<48, 256, 0, stream>>>(skw, wt_sk, 64, 192);
  // gn2 + silu -> NHWC bf16
  stats1_kernel<<<NBL * 32, 256, 0, stream>>>(h1, NC * NHW, part);
  stats2_kernel<<<NBL, 64, 0, stream>>>(part, NC * NHW, stats + 32, stats + 40);
  gnsilu_t_kernel<NC><<<NBL * 64, 256, 0, stream>>>(h1, gn2g, gn2b, stats + 32, act2b);
  conv_mfma_kernel<NC><<<NBL * 64 * 2, 256, 0, stream>>>(act2b, wb2, c2b, h2);
  // skip 1x1 + residual + NHWC transpose
  skip_kernel<<<NBL * 64, 256, 0, stream>>>(xcat, h2, wt_sk, skb, xres);
  wtrans_kernel<<<64, 256, 0, stream>>>(ipw, wt_ip, 256, 64);
  // SS2D
  inproj_kernel<<<1536, 256, 0, stream>>>(xres, ln1g, ln1b, wt_ip, xxin, zbuf);
  dwconv_kernel<<<12288, 256, 0, stream>>>(xxin, dww, dwb, xxc);
  wtrans_kernel<<<32, 256, 0, stream>>>(opw, wt_op, 64, 128);
  wtrans_kernel<<<16, 256, 0, stream>>>(f1w, wt_f1, 64, 64);
  wtrans_kernel<<<16, 256, 0, stream>>>(f2w, wt_f2, 64, 64);
  xdbl_kernel<<<NBL * 2 * 64, 256, 0, stream>>>(xxc, xpw, xdbl);
  // chunked scan (128 chunks of 32); H/HS/ys in bf16
  scan_pass1_kernel<<<24 * NCH, 128, 0, stream>>>(xdbl, xxc, dtw, dtb, Alog, chunkSdt, chunkH16);
  scan_pass2_kernel<<<192, 256, 0, stream>>>(chunkSdt, chunkH16, Alog, chunkHS16);
  scan_pass3_kernel<<<24 * NCH, 128, 0, stream>>>(xdbl, xxc, dtw, dtb, Alog, chunkHS16, ys16);
  // fused combine + out_norm + gate + out_proj + residual
  outproj_kernel<<<1536, 256, 0, stream>>>(ys16, xxc, Dsp, zbuf, ong, onb, wt_op, xres, x1);
  // MLP + residual + fused NCHW output transpose
  mlp_kernel<<<1536, 256, 0, stream>>>(x1, ln2g, ln2b, wt_f1, f1b, wt_f2, f2b, out);
}

// Round 13
// 324.231 us; speedup vs baseline: 1.1067x; 1.0608x over previous
//
#include <hip/hip_runtime.h>
#include <hip/hip_bf16.h>

typedef unsigned short ushortT;
typedef short short8v __attribute__((ext_vector_type(8)));
typedef float float4v __attribute__((ext_vector_type(4)));

// Problem constants
#define NBL 6      // B*LEN
#define NC 64
#define NC3 192
#define NHW 4096   // 64*64
#define NDI 128
#define NNS 16
#define NDR 4
#define NK 4
#define NL 4096
#define NCH 128    // scan chunks
#define SCLEN 32   // chunk length
#define NSTATE 49152  // 24 bk * 128 d * 16 n
#define NSAMP 262144  // 64*4096 per-sample reduction size

// workspace offsets in floats
static const size_t F_XCAT  = 0;          // free scratch; chunkHS16 during scan
static const size_t F_ACT1  = 4718592;    // act1b bf16 NHWC
static const size_t F_H1    = 9437184;    // 1,572,864
static const size_t F_ACT2  = 11010048;   // act2b bf16 NHWC
static const size_t F_H2    = 12582912;   // 1,572,864
static const size_t F_XRES  = 14155776;   // 1,572,864
static const size_t F_XXIN  = 15728640;   // 3,145,728
static const size_t F_Z     = 18874368;   // 3,145,728
static const size_t F_XXC   = 22020096;   // 3,145,728
static const size_t F_XDBL  = 25165824;   // 3,538,944
static const size_t F_YS    = 28704768;   // 12,582,912: ys-bf16 | chunkH16 | sdt
static const size_t F_WTS   = 41287680;   // 3,145,728: all transposed weights + conv packs
static const size_t F_X1    = 44433408;   // 1,572,864
static const size_t F_X2    = 46006272;   // 1,572,864 (stats partials)
static const size_t F_STATS = 47579136;   // 48
static const size_t F_TOTAL = 47579184;   // floats (~190.3 MB)

__device__ __forceinline__ float wred64(float v) {
#pragma unroll
  for (int m = 32; m; m >>= 1) v += __shfl_xor(v, m, 64);
  return v;
}

__device__ __forceinline__ float silu(float v) {
  return v / (1.f + __expf(-v));
}

__device__ __forceinline__ ushortT f2bf(float f) {
  unsigned int u = __builtin_bit_cast(unsigned int, f);
  unsigned int r = (u + 0x7FFFu + ((u >> 16) & 1u)) >> 16;
  return (ushortT)r;
}

__device__ __forceinline__ float bf2f(ushortT u) {
  return __builtin_bit_cast(float, (unsigned int)u << 16);
}

__device__ __forceinline__ int map_pos(int k, int l) {
  if (k == 0) return l;
  if (k == 1) return ((l & 63) << 6) | (l >> 6);
  if (k == 2) return 4095 - l;
  int lp = 4095 - l;
  return ((lp & 63) << 6) | (lp >> 6);
}

__device__ __forceinline__ float softplus_fast(float a) {
  float t = exp2f(a * 1.44269504f);
  float r = 0.69314718f * __log2f(1.f + t);
  return (a > 20.f) ? a : r;
}

// powers E^1..E^16 via mul tree (for geometric A: a_n = (n+1)*a_1)
__device__ __forceinline__ void pow_tree(float E1, float4v& e0, float4v& e1,
                                         float4v& e2, float4v& e3) {
  float E2 = E1 * E1, E3 = E2 * E1, E4 = E2 * E2;
  float E5 = E4 * E1, E6 = E4 * E2, E7 = E4 * E3, E8 = E4 * E4;
  e0[0] = E1; e0[1] = E2; e0[2] = E3; e0[3] = E4;
  e1[0] = E5; e1[1] = E6; e1[2] = E7; e1[3] = E8;
  e2[0] = E8 * E1; e2[1] = E8 * E2; e2[2] = E8 * E3; e2[3] = E8 * E4;
  e3[0] = E8 * E5; e3[1] = E8 * E6; e3[2] = E8 * E7; e3[3] = E8 * E8;
}

// ---- batched weight prep: 5 transposes + 2 MFMA packs in one launch ----
__global__ __launch_bounds__(256) void prep_kernel(const float* __restrict__ skw,
                                                   const float* __restrict__ ipw,
                                                   const float* __restrict__ opw,
                                                   const float* __restrict__ f1w,
                                                   const float* __restrict__ f2w,
                                                   const float* __restrict__ c1w,
                                                   const float* __restrict__ c2w,
                                                   float* __restrict__ wt_sk,
                                                   float* __restrict__ wt_ip,
                                                   float* __restrict__ wt_op,
                                                   float* __restrict__ wt_f1,
                                                   float* __restrict__ wt_f2,
                                                   ushortT* __restrict__ wb1,
                                                   ushortT* __restrict__ wb2) {
  int bi = blockIdx.x;
  int t = threadIdx.x;
  if (bi < 48) {                    // skw 64x192 -> [192][64]
    int id = bi * 256 + t;
    int c = id / 64, o = id % 64;
    wt_sk[id] = skw[o * 192 + c];
  } else if (bi < 112) {            // ipw 256x64 -> [64][256]
    int id = (bi - 48) * 256 + t;
    int c = id / 256, o = id % 256;
    wt_ip[id] = ipw[o * 64 + c];
  } else if (bi < 144) {            // opw 64x128 -> [128][64]
    int id = (bi - 112) * 256 + t;
    int c = id / 64, o = id % 64;
    wt_op[id] = opw[o * 128 + c];
  } else if (bi < 160) {            // f1w 64x64
    int id = (bi - 144) * 256 + t;
    int c = id / 64, o = id % 64;
    wt_f1[id] = f1w[o * 64 + c];
  } else if (bi < 176) {            // f2w 64x64
    int id = (bi - 160) * 256 + t;
    int c = id / 64, o = id % 64;
    wt_f2[id] = f2w[o * 64 + c];
  } else if (bi < 608) {            // conv1 pack (CIN=192, KT=6)
    int id = (bi - 176) * 256 + t;
    int j = id & 7, lane = (id >> 3) & 63, nt = (id >> 9) & 3;
    int rest = id >> 11;
    int kt = rest % 6, tap = rest / 6;
    int oc = nt * 16 + (lane & 15);
    int ic = kt * 32 + ((lane >> 4) << 3) + j;
    int r = tap / 3, s = tap % 3;
    wb1[id] = f2bf(c1w[(((size_t)oc * 192 + ic) * 3 + r) * 3 + s]);
  } else {                          // conv2 pack (CIN=64, KT=2)
    int id = (bi - 608) * 256 + t;
    int j = id & 7, lane = (id >> 3) & 63, nt = (id >> 9) & 3;
    int rest = id >> 11;
    int kt = rest % 2, tap = rest / 2;
    int oc = nt * 16 + (lane & 15);
    int ic = kt * 32 + ((lane >> 4) << 3) + j;
    int r = tap / 3, s = tap % 3;
    wb2[id] = f2bf(c2w[(((size_t)oc * 64 + ic) * 3 + r) * 3 + s]);
  }
}

// ---- batched per-sample sums: img(6) + dz(2) + sg(2), all n=NSAMP ----
__global__ __launch_bounds__(256) void stats1_all_kernel(const float* __restrict__ img,
                                                         const float* __restrict__ dz,
                                                         const float* __restrict__ sg,
                                                         double* __restrict__ part) {
  int bi = blockIdx.x;
  int s = bi >> 5, j = bi & 31;
  const float* srcb = (s < 6) ? (img + (size_t)s * NSAMP)
                   : (s < 8) ? (dz + (size_t)(s - 6) * NSAMP)
                             : (sg + (size_t)(s - 8) * NSAMP);
  int slice = NSAMP >> 5;
  const float4* p = (const float4*)(srcb + (size_t)j * slice);
  int n4 = slice >> 2;
  double dsum = 0.0, dsq = 0.0;
  for (int i = threadIdx.x; i < n4; i += 256) {
    float4 v = p[i];
    dsum += (double)((v.x + v.y) + (v.z + v.w));
    dsq += (double)v.x * v.x + (double)v.y * v.y + (double)v.z * v.z + (double)v.w * v.w;
  }
  __shared__ double s1[256], s2[256];
  s1[threadIdx.x] = dsum; s2[threadIdx.x] = dsq;
  __syncthreads();
  for (int off = 128; off; off >>= 1) {
    if (threadIdx.x < off) { s1[threadIdx.x] += s1[threadIdx.x + off]; s2[threadIdx.x] += s2[threadIdx.x + off]; }
    __syncthreads();
  }
  if (threadIdx.x == 0) { part[2 * bi] = s1[0]; part[2 * bi + 1] = s2[0]; }
}

// generic stats1 (for h1 / gn2)
__global__ __launch_bounds__(256) void stats1_kernel(const float* __restrict__ in, int n,
                                                     double* __restrict__ part) {
  int bi = blockIdx.x;
  int s = bi >> 5, j = bi & 31;
  int slice = n >> 5;
  const float4* p = (const float4*)(in + (size_t)s * n + (size_t)j * slice);
  int n4 = slice >> 2;
  double dsum = 0.0, dsq = 0.0;
  for (int i = threadIdx.x; i < n4; i += 256) {
    float4 v = p[i];
    dsum += (double)((v.x + v.y) + (v.z + v.w));
    dsq += (double)v.x * v.x + (double)v.y * v.y + (double)v.z * v.z + (double)v.w * v.w;
  }
  __shared__ double s1[256], s2[256];
  s1[threadIdx.x] = dsum; s2[threadIdx.x] = dsq;
  __syncthreads();
  for (int off = 128; off; off >>= 1) {
    if (threadIdx.x < off) { s1[threadIdx.x] += s1[threadIdx.x + off]; s2[threadIdx.x] += s2[threadIdx.x + off]; }
    __syncthreads();
  }
  if (threadIdx.x == 0) { part[2 * bi] = s1[0]; part[2 * bi + 1] = s2[0]; }
}

__global__ __launch_bounds__(64) void stats2_kernel(const double* __restrict__ part, int n,
                                                    float* __restrict__ mean_out,
                                                    float* __restrict__ rstd_out) {
  int s = blockIdx.x;
  int lane = threadIdx.x;
  double sum = 0.0, sq = 0.0;
  if (lane < 32) { sum = part[2 * (s * 32 + lane)]; sq = part[2 * (s * 32 + lane) + 1]; }
#pragma unroll
  for (int m = 16; m; m >>= 1) { sum += __shfl_xor(sum, m, 64); sq += __shfl_xor(sq, m, 64); }
  if (lane == 0) {
    double mean = sum / n;
    double var = sq / n - mean * mean;
    mean_out[s] = (float)mean;
    rstd_out[s] = (float)(1.0 / sqrt(var + 1e-5));
  }
}

// blocks 0-5: img instance stats -> stats[0..6)=mean, stats[8..14)=rstd
// block 6: analytic gn1 cat-stats per bl -> stats[16+bl]=mean, stats[24+bl]=rstd
__global__ __launch_bounds__(64) void stats2_comb_kernel(const double* __restrict__ part,
                                                         float* __restrict__ stats) {
  int s = blockIdx.x;
  int lane = threadIdx.x;
  if (s < 6) {
    double sum = 0.0, sq = 0.0;
    if (lane < 32) { sum = part[2 * (s * 32 + lane)]; sq = part[2 * (s * 32 + lane) + 1]; }
#pragma unroll
    for (int m = 16; m; m >>= 1) { sum += __shfl_xor(sum, m, 64); sq += __shfl_xor(sq, m, 64); }
    if (lane == 0) {
      double mean = sum / NSAMP;
      double var = sq / NSAMP - mean * mean;
      stats[s] = (float)mean;
      stats[8 + s] = (float)(1.0 / sqrt(var + 1e-5));
    }
    return;
  }
  // block 6: serial on lane 0 (tiny)
  if (lane == 0) {
    double sums[10], sqs[10];
    for (int q = 0; q < 10; ++q) {
      double a = 0.0, b2 = 0.0;
      for (int j = 0; j < 32; ++j) { a += part[2 * (q * 32 + j)]; b2 += part[2 * (q * 32 + j) + 1]; }
      sums[q] = a; sqs[q] = b2;
    }
    const double N = (double)NSAMP;
    for (int bl = 0; bl < 6; ++bl) {
      int b = bl / 3;
      double mi = sums[bl] / N;
      double vi = sqs[bl] / N - mi * mi;
      double ssq_norm = N * (vi / (vi + 1e-5));   // sum of squares of instance-normed img
      double sum_cat = sums[6 + b] + sums[8 + b]; // imgnorm sums to 0
      double ssq_cat = sqs[6 + b] + ssq_norm + sqs[8 + b];
      double mean = sum_cat / (3.0 * N);
      double var = ssq_cat / (3.0 * N) - mean * mean;
      stats[16 + bl] = (float)mean;
      stats[24 + bl] = (float)(1.0 / sqrt(var + 1e-5));
    }
  }
}

// gn1 + silu over the virtual concat [dz, imgnorm, sg] -> NHWC bf16. grid NBL*64.
__global__ __launch_bounds__(256) void gnsilu_cat_kernel(const float* __restrict__ img,
                                                         const float* __restrict__ dz,
                                                         const float* __restrict__ sg,
                                                         const float* __restrict__ g,
                                                         const float* __restrict__ b,
                                                         const float* __restrict__ stats,
                                                         ushortT* __restrict__ outb) {
  int bi = blockIdx.x;
  int bl = bi >> 6, h = bi & 63;
  int bb = bl / 3;
  __shared__ ushortT tile[NC3][66];
  float mi = stats[bl], rsi = stats[8 + bl];
  float mc = stats[16 + bl], rsc = stats[24 + bl];
  int t = threadIdx.x;
  for (int idx = t; idx < NC3 * 64; idx += 256) {
    int ch = idx >> 6, w = idx & 63;
    int hw = (h << 6) + w;
    float v;
    if (ch < 64) v = dz[((size_t)bb * NC + ch) * NHW + hw];
    else if (ch < 128) v = (img[((size_t)bl * NC + (ch - 64)) * NHW + hw] - mi) * rsi;
    else v = sg[((size_t)bb * NC + (ch - 128)) * NHW + hw];
    v = (v - mc) * rsc * g[ch] + b[ch];
    tile[ch][w] = f2bf(silu(v));
  }
  __syncthreads();
  constexpr int C8 = NC3 / 8;
  for (int idx = t; idx < 64 * C8; idx += 256) {
    int w = idx / C8, c8 = idx % C8;
    short8v v;
#pragma unroll
    for (int j = 0; j < 8; ++j) v[j] = (short)tile[c8 * 8 + j][w];
    *(short8v*)&outb[(size_t)(bl * 4096 + h * 64 + w) * NC3 + c8 * 8] = v;
  }
}

// gn2 + silu + NCHW->NHWC bf16 (64ch). grid NBL*64.
__global__ __launch_bounds__(256) void gnsilu_t_kernel(const float* __restrict__ in,
                                                       const float* __restrict__ g,
                                                       const float* __restrict__ b,
                                                       const float* __restrict__ stats,
                                                       ushortT* __restrict__ outb) {
  int bi = blockIdx.x;
  int bl = bi >> 6, h = bi & 63;
  __shared__ ushortT tile[NC][66];
  float m = stats[bl], rs = stats[8 + bl];
  int t = threadIdx.x;
  for (int idx = t; idx < NC * 64; idx += 256) {
    int ch = idx >> 6, w = idx & 63;
    float v = in[(((size_t)bl * NC + ch) << 12) + (h << 6) + w];
    v = (v - m) * rs * g[ch] + b[ch];
    tile[ch][w] = f2bf(silu(v));
  }
  __syncthreads();
  constexpr int C8 = NC / 8;
  for (int idx = t; idx < 64 * C8; idx += 256) {
    int w = idx / C8, c8 = idx % C8;
    short8v v;
#pragma unroll
    for (int j = 0; j < 8; ++j) v[j] = (short)tile[c8 * 8 + j][w];
    *(short8v*)&outb[(size_t)(bl * 4096 + h * 64 + w) * NC + c8 * 8] = v;
  }
}

// Implicit-GEMM 3x3 SAME conv via bf16 MFMA, f32 accumulate.
template <int CIN>
__global__ __launch_bounds__(256) void conv_mfma_kernel(const ushortT* __restrict__ actb,
                                                        const ushortT* __restrict__ wb,
                                                        const float* __restrict__ bias,
                                                        float* __restrict__ out) {
  constexpr int KT = CIN / 32;
  constexpr int STRIDE = CIN + 8;
  constexpr int C8 = CIN / 8;
  int bi = blockIdx.x;
  int nh = bi & 1;
  int h = (bi >> 1) & 63;
  int bl = bi >> 7;
  int t = threadIdx.x;
  int wv = t >> 6, lane = t & 63;
  __shared__ ushortT lds[66 * STRIDE];
  float4v acc0 = {0.f, 0.f, 0.f, 0.f};
  float4v acc1 = {0.f, 0.f, 0.f, 0.f};
  int lrow = lane & 15;
  int lk = (lane >> 4) << 3;
  for (int dy = 0; dy < 3; ++dy) {
    int hh = h + dy - 1;
    bool valid = (hh >= 0) && (hh < 64);
    int hc = valid ? hh : 0;
    if (dy) __syncthreads();
    const ushortT* src = actb + (size_t)(bl * 4096 + hc * 64) * CIN;
    for (int idx = t; idx < 64 * C8; idx += 256) {
      int w = idx / C8, c8 = idx % C8;
      short8v v = {0, 0, 0, 0, 0, 0, 0, 0};
      if (valid) v = *(const short8v*)&src[(size_t)w * CIN + c8 * 8];
      *(short8v*)&lds[(w + 1) * STRIDE + c8 * 8] = v;
    }
    if (t < 2 * C8) {
      int which = t / C8, c8 = t % C8;
      short8v z = {0, 0, 0, 0, 0, 0, 0, 0};
      *(short8v*)&lds[(which ? 65 : 0) * STRIDE + c8 * 8] = z;
    }
    __syncthreads();
    for (int dx = 0; dx < 3; ++dx) {
      int tap = dy * 3 + dx;
      int wl = (wv << 4) + lrow + dx;
#pragma unroll
      for (int kt = 0; kt < KT; ++kt) {
        short8v a = *(const short8v*)&lds[wl * STRIDE + kt * 32 + lk];
        const ushortT* wp = wb + ((size_t)(((tap * KT + kt) * 4 + (nh << 1)) * 64 + lane) << 3);
        short8v b0 = *(const short8v*)&wp[0];
        short8v b1 = *(const short8v*)&wp[512];
        acc0 = __builtin_amdgcn_mfma_f32_16x16x32_bf16(a, b0, acc0, 0, 0, 0);
        acc1 = __builtin_amdgcn_mfma_f32_16x16x32_bf16(a, b1, acc1, 0, 0, 0);
      }
    }
  }
  int oc0 = (nh << 5) + lrow;
  int oc1 = oc0 + 16;
  int w0 = (wv << 4) + ((lane >> 4) << 2);
  float bv0 = bias[oc0], bv1 = bias[oc1];
  float4 o0 = make_float4(acc0[0] + bv0, acc0[1] + bv0, acc0[2] + bv0, acc0[3] + bv0);
  float4 o1 = make_float4(acc1[0] + bv1, acc1[1] + bv1, acc1[2] + bv1, acc1[3] + bv1);
  *(float4*)&out[(((size_t)bl * 64 + oc0) << 12) + (h << 6) + w0] = o0;
  *(float4*)&out[(((size_t)bl * 64 + oc1) << 12) + (h << 6) + w0] = o1;
}

// x_res[bl][p][oc] = h2 + 1x1skip(virtual concat) + skb  (NHWC out)
__global__ __launch_bounds__(256) void skip_kernel(const float* __restrict__ img,
                                                   const float* __restrict__ dz,
                                                   const float* __restrict__ sg,
                                                   const float* __restrict__ stats,
                                                   const float* __restrict__ h2,
                                                   const float* __restrict__ skwt,
                                                   const float* __restrict__ skb,
                                                   float* __restrict__ xres) {
  int bi = blockIdx.x;
  int bl = bi >> 6, h = bi & 63;
  int bb = bl / 3;
  int t = threadIdx.x;
  int oc = t & 63, w0 = (t >> 6) << 4;
  float mi = stats[bl], rsi = stats[8 + bl];
  __shared__ float lds[64][64];
  float acc[16];
#pragma unroll
  for (int i = 0; i < 16; ++i) acc[i] = 0.f;
  for (int cc = 0; cc < 3; ++cc) {
    __syncthreads();
    for (int idx = t; idx < 4096; idx += 256) {
      int ch = idx >> 6, w = idx & 63;
      int hw = (h << 6) + w;
      float v;
      if (cc == 0) v = dz[((size_t)bb * NC + ch) * NHW + hw];
      else if (cc == 1) v = (img[((size_t)bl * NC + ch) * NHW + hw] - mi) * rsi;
      else v = sg[((size_t)bb * NC + ch) * NHW + hw];
      lds[ch][w] = v;
    }
    __syncthreads();
    for (int ch = 0; ch < 64; ++ch) {
      float wv = skwt[((cc << 6) + ch) * 64 + oc];
#pragma unroll
      for (int i = 0; i < 16; ++i) acc[i] += wv * lds[ch][w0 + i];
    }
  }
  float bv = skb[oc];
  int p0 = (h << 6) + w0;
#pragma unroll
  for (int i = 0; i < 16; ++i) {
    float hv = h2[(((size_t)bl * 64 + oc) << 12) + p0 + i];
    xres[((size_t)bl * NHW + p0 + i) * 64 + oc] = acc[i] + bv + hv;
  }
}

// LN(ln1) + 64->256 proj; 16 positions per block; wt[c(64)][oc(256)]. grid 1536.
__global__ __launch_bounds__(256) void inproj_kernel(const float* __restrict__ xres,
                                                     const float* __restrict__ g,
                                                     const float* __restrict__ b,
                                                     const float* __restrict__ wt,
                                                     float* __restrict__ xxin,
                                                     float* __restrict__ z) {
  int wv = threadIdx.x >> 6, lane = threadIdx.x & 63;
  size_t pi0 = (size_t)blockIdx.x << 4;
  __shared__ float xb[64][16];
  float gv = g[lane], bv = b[lane];
#pragma unroll
  for (int j = 0; j < 4; ++j) {
    int p = (wv << 2) + j;
    float x = xres[(pi0 + p) * 64 + lane];
    float s = wred64(x);
    float s2 = wred64(x * x);
    float m = s * (1.f / 64), var = s2 * (1.f / 64) - m * m;
    float rstd = rsqrtf(var + 1e-5f);
    xb[lane][p] = (x - m) * rstd * gv + bv;
  }
  __syncthreads();
  int oc = (wv << 6) + lane;
  float4v a0 = {0.f, 0.f, 0.f, 0.f}, a1 = a0, a2 = a0, a3 = a0;
  for (int c = 0; c < 64; ++c) {
    float w = wt[(c << 8) + oc];
    const float4v* xr = (const float4v*)&xb[c][0];
    a0 += w * xr[0];
    a1 += w * xr[1];
    a2 += w * xr[2];
    a3 += w * xr[3];
  }
  float acc[16];
  *(float4v*)&acc[0] = a0;
  *(float4v*)&acc[4] = a1;
  *(float4v*)&acc[8] = a2;
  *(float4v*)&acc[12] = a3;
  float* dst = (oc < 128) ? xxin : z;
  int oco = (oc < 128) ? oc : (oc - 128);
#pragma unroll
  for (int p = 0; p < 16; ++p) dst[((pi0 + p) << 7) + oco] = acc[p];
}

// depthwise 3x3 SAME + bias + silu on NHWC [bl][p][128]
__global__ __launch_bounds__(256) void dwconv_kernel(const float* __restrict__ xx,
                                                     const float* __restrict__ w,
                                                     const float* __restrict__ b,
                                                     float* __restrict__ out) {
  size_t gid = (size_t)blockIdx.x * 256 + threadIdx.x;
  int d = gid & 127;
  size_t pi = gid >> 7;
  int p = (int)(pi & 4095);
  int bl = (int)(pi >> 12);
  int h = p >> 6, wq = p & 63;
  float acc = b[d];
  const float* wr = w + d * 9;
#pragma unroll
  for (int dy = -1; dy <= 1; ++dy) {
    int hh = h + dy;
    if (hh < 0 || hh >= 64) continue;
#pragma unroll
    for (int dx = -1; dx <= 1; ++dx) {
      int ww = wq + dx;
      if (ww < 0 || ww >= 64) continue;
      acc += wr[(dy + 1) * 3 + (dx + 1)] * xx[(((size_t)bl << 12) + (hh << 6) + ww) * 128 + d];
    }
  }
  out[pi * 128 + d] = silu(acc);
}

// x_dbl via shared hw/wh tile; computes forward k and reversed k+2 per block.
__global__ __launch_bounds__(256) void xdbl_kernel(const float* __restrict__ xxc,
                                                   const float* __restrict__ xpw,
                                                   float* __restrict__ xdbl) {
  int bi = blockIdx.x;
  int lt = bi & 63;
  int korder = (bi >> 6) & 1;
  int bl = bi >> 7;
  int lbase = lt << 6;
  __shared__ float xs[64 * 128];
  int t = threadIdx.x;
#pragma unroll
  for (int it = 0; it < 8; ++it) {
    int idx = it * 256 + t;
    int i = idx >> 5, d4 = idx & 31;
    int l = lbase + i;
    int pos = korder ? (((l & 63) << 6) | (l >> 6)) : l;
    float4 v = *(const float4*)&xxc[((size_t)bl * NHW + pos) * 128 + (d4 << 2)];
    int slot = d4 ^ (i & 7);
    *(float4*)&xs[i * 128 + (slot << 2)] = v;
  }
  __syncthreads();
  int wv = __builtin_amdgcn_readfirstlane(t >> 6);
  int lane = t & 63;
  int k_w = korder + ((wv >= 2) ? 2 : 0);
  int c0 = (wv & 1) * 18;
  float acc[18];
#pragma unroll
  for (int j = 0; j < 18; ++j) acc[j] = 0.f;
  const float* wbase = xpw + (size_t)(k_w * 36 + c0) * 128;
  for (int d4 = 0; d4 < 32; ++d4) {
    int slot = d4 ^ (lane & 7);
    float4 x4 = *(const float4*)&xs[lane * 128 + (slot << 2)];
#pragma unroll
    for (int j = 0; j < 18; ++j) {
      float4 w4 = *(const float4*)&wbase[j * 128 + (d4 << 2)];
      acc[j] += w4.x * x4.x + w4.y * x4.y + w4.z * x4.z + w4.w * x4.w;
    }
  }
  int lout = (k_w < 2) ? (lbase + lane) : (4095 - lbase - lane);
  size_t obase = ((size_t)(bl * 4 + k_w) * 36 + c0) * (size_t)NL + lout;
#pragma unroll
  for (int j = 0; j < 18; ++j)
    xdbl[obase + (size_t)j * NL] = acc[j];
}

// ---- chunked selective scan ----
__global__ __launch_bounds__(128) void scan_pass1_kernel(const float* __restrict__ xdbl,
                                                         const float* __restrict__ xxc,
                                                         const float* __restrict__ dtw,
                                                         const float* __restrict__ dtb,
                                                         const float* __restrict__ Alog,
                                                         float* __restrict__ chunkSdt,
                                                         ushortT* __restrict__ chunkH16) {
  int bi = blockIdx.x;
  int chunk = bi & (NCH - 1);
  int bk = bi >> 7;
  int k = bk & 3, bl = bk >> 2;
  int d = threadIdx.x;
  float4 wv = *(const float4*)(dtw + (size_t)(((k << 7) + d) << 2));
  float bias = dtb[(k << 7) + d];
  const float* ar = Alog + (size_t)(((k << 7) + d) << 4);
  float a1v = -__expf(ar[0]) * 1.44269504f;
  bool geom = true;
#pragma unroll
  for (int n = 1; n < 16; ++n) {
    float an = -__expf(ar[n]) * 1.44269504f;
    geom = geom && (fabsf(an - (float)(n + 1) * a1v) <= 1e-3f * fabsf((float)(n + 1) * a1v) + 1e-6f);
  }
  __shared__ float xd[SCLEN][20];
  int l0 = chunk << 5;
  for (int idx = threadIdx.x; idx < 20 * SCLEN; idx += 128) {
    int c = idx >> 5, li = idx & 31;
    xd[li][c] = xdbl[((size_t)bk * 36 + c) * (size_t)NL + l0 + li];
  }
  __syncthreads();
  const float* uB = xxc + ((size_t)bl << 19) + d;
  float4v h0 = {0.f, 0.f, 0.f, 0.f}, h1 = h0, h2 = h0, h3 = h0;
  float sdt = 0.f;
  float u_nxt = uB[(size_t)map_pos(k, l0) << 7];
  if (geom) {
#pragma unroll 2
    for (int li = 0; li < SCLEN; ++li) {
      float u = u_nxt;
      int nl = (li < SCLEN - 1) ? (li + 1) : (SCLEN - 1);
      u_nxt = uB[(size_t)map_pos(k, l0 + nl) << 7];
      const float4v* row = (const float4v*)&xd[li][0];
      float4v q0 = row[0];
      float accq = bias + wv.x * q0[0] + wv.y * q0[1] + wv.z * q0[2] + wv.w * q0[3];
      float dt = softplus_fast(accq);
      float dtu = dt * u;
      sdt += dt;
      float4v b0 = row[1], b1 = row[2], b2 = row[3], b3 = row[4];
      float4v e0, e1, e2, e3;
      pow_tree(exp2f(a1v * dt), e0, e1, e2, e3);
      h0 = e0 * h0 + dtu * b0;
      h1 = e1 * h1 + dtu * b1;
      h2 = e2 * h2 + dtu * b2;
      h3 = e3 * h3 + dtu * b3;
    }
  } else {
    float4v a0v, a1q, a2q, a3q;
#pragma unroll
    for (int j = 0; j < 4; ++j) {
      a0v[j] = -__expf(ar[j]) * 1.44269504f;
      a1q[j] = -__expf(ar[4 + j]) * 1.44269504f;
      a2q[j] = -__expf(ar[8 + j]) * 1.44269504f;
      a3q[j] = -__expf(ar[12 + j]) * 1.44269504f;
    }
    for (int li = 0; li < SCLEN; ++li) {
      float u = u_nxt;
      int nl = (li < SCLEN - 1) ? (li + 1) : (SCLEN - 1);
      u_nxt = uB[(size_t)map_pos(k, l0 + nl) << 7];
      const float4v* row = (const float4v*)&xd[li][0];
      float4v q0 = row[0];
      float accq = bias + wv.x * q0[0] + wv.y * q0[1] + wv.z * q0[2] + wv.w * q0[3];
      float dt = softplus_fast(accq);
      float dtu = dt * u;
      sdt += dt;
      float4v b0 = row[1], b1 = row[2], b2 = row[3], b3 = row[4];
      float4v e0, e1, e2, e3;
#pragma unroll
      for (int j = 0; j < 4; ++j) {
        e0[j] = exp2f(a0v[j] * dt);
        e1[j] = exp2f(a1q[j] * dt);
        e2[j] = exp2f(a2q[j] * dt);
        e3[j] = exp2f(a3q[j] * dt);
      }
      h0 = e0 * h0 + dtu * b0;
      h1 = e1 * h1 + dtu * b1;
      h2 = e2 * h2 + dtu * b2;
      h3 = e3 * h3 + dtu * b3;
    }
  }
  size_t base = (size_t)chunk * NSTATE + (((size_t)bk << 7) + (size_t)d) * 16;
  chunkSdt[(size_t)chunk * 3072 + (bk << 7) + d] = sdt;
  short8v s0, s1;
#pragma unroll
  for (int j = 0; j < 4; ++j) {
    s0[j] = (short)f2bf(h0[j]);
    s0[4 + j] = (short)f2bf(h1[j]);
    s1[j] = (short)f2bf(h2[j]);
    s1[4 + j] = (short)f2bf(h3[j]);
  }
  *(short8v*)&chunkH16[base + 0] = s0;
  *(short8v*)&chunkH16[base + 8] = s1;
}

__global__ __launch_bounds__(256) void scan_pass2_kernel(const float* __restrict__ chunkSdt,
                                                         const ushortT* __restrict__ chunkH16,
                                                         const float* __restrict__ Alog,
                                                         ushortT* __restrict__ chunkHS16) {
  size_t state = (size_t)blockIdx.x * 256 + threadIdx.x;
  float an = -__expf(Alog[state & 8191]) * 1.44269504f;
  int kd = (int)(state >> 4);
  float h = 0.f;
  for (int j = 0; j < NCH; ++j) {
    size_t idx = (size_t)j * NSTATE + state;
    chunkHS16[idx] = f2bf(h);
    float sdt = chunkSdt[(size_t)j * 3072 + kd];
    h = exp2f(an * sdt) * h + bf2f(chunkH16[idx]);
  }
}

__global__ __launch_bounds__(128) void scan_pass3_kernel(const float* __restrict__ xdbl,
                                                         const float* __restrict__ xxc,
                                                         const float* __restrict__ dtw,
                                                         const float* __restrict__ dtb,
                                                         const float* __restrict__ Alog,
                                                         const ushortT* __restrict__ chunkHS16,
                                                         ushortT* __restrict__ ys16) {
  int bi = blockIdx.x;
  int chunk = bi & (NCH - 1);
  int bk = bi >> 7;
  int k = bk & 3, bl = bk >> 2;
  int d = threadIdx.x;
  float4 wv = *(const float4*)(dtw + (size_t)(((k << 7) + d) << 2));
  float bias = dtb[(k << 7) + d];
  const float* ar = Alog + (size_t)(((k << 7) + d) << 4);
  float a1v = -__expf(ar[0]) * 1.44269504f;
  bool geom = true;
#pragma unroll
  for (int n = 1; n < 16; ++n) {
    float an = -__expf(ar[n]) * 1.44269504f;
    geom = geom && (fabsf(an - (float)(n + 1) * a1v) <= 1e-3f * fabsf((float)(n + 1) * a1v) + 1e-6f);
  }
  __shared__ float xd[SCLEN][40];
  int l0 = chunk << 5;
  for (int idx = threadIdx.x; idx < 36 * SCLEN; idx += 128) {
    int c = idx >> 5, li = idx & 31;
    xd[li][c] = xdbl[((size_t)bk * 36 + c) * (size_t)NL + l0 + li];
  }
  __syncthreads();
  const float* uB = xxc + ((size_t)bl << 19) + d;
  ushortT* yB = ys16 + ((size_t)bk << 19) + d;
  size_t base = (size_t)chunk * NSTATE + (((size_t)bk << 7) + (size_t)d) * 16;
  float4v h0, h1, h2, h3;
  {
    short8v s0 = *(const short8v*)&chunkHS16[base + 0];
    short8v s1 = *(const short8v*)&chunkHS16[base + 8];
#pragma unroll
    for (int j = 0; j < 4; ++j) {
      h0[j] = bf2f((ushortT)s0[j]);
      h1[j] = bf2f((ushortT)s0[4 + j]);
      h2[j] = bf2f((ushortT)s1[j]);
      h3[j] = bf2f((ushortT)s1[4 + j]);
    }
  }
  float u_nxt = uB[(size_t)map_pos(k, l0) << 7];
  if (geom) {
#pragma unroll 2
    for (int li = 0; li < SCLEN; ++li) {
      float u = u_nxt;
      int nl = (li < SCLEN - 1) ? (li + 1) : (SCLEN - 1);
      u_nxt = uB[(size_t)map_pos(k, l0 + nl) << 7];
      const float4v* row = (const float4v*)&xd[li][0];
      float4v q0 = row[0];
      float accq = bias + wv.x * q0[0] + wv.y * q0[1] + wv.z * q0[2] + wv.w * q0[3];
      float dt = softplus_fast(accq);
      float dtu = dt * u;
      float4v b0 = row[1], b1 = row[2], b2 = row[3], b3 = row[4];
      float4v c0 = row[5], c1 = row[6], c2 = row[7], c3 = row[8];
      float4v e0, e1, e2, e3;
      pow_tree(exp2f(a1v * dt), e0, e1, e2, e3);
      h0 = e0 * h0 + dtu * b0;
      h1 = e1 * h1 + dtu * b1;
      h2 = e2 * h2 + dtu * b2;
      h3 = e3 * h3 + dtu * b3;
      float4v sy = h0 * c0;
      sy += h1 * c1;
      sy += h2 * c2;
      sy += h3 * c3;
      yB[(size_t)(l0 + li) << 7] = f2bf((sy[0] + sy[1]) + (sy[2] + sy[3]));
    }
  } else {
    float4v a0v, a1q, a2q, a3q;
#pragma unroll
    for (int j = 0; j < 4; ++j) {
      a0v[j] = -__expf(ar[j]) * 1.44269504f;
      a1q[j] = -__expf(ar[4 + j]) * 1.44269504f;
      a2q[j] = -__expf(ar[8 + j]) * 1.44269504f;
      a3q[j] = -__expf(ar[12 + j]) * 1.44269504f;
    }
    for (int li = 0; li < SCLEN; ++li) {
      float u = u_nxt;
      int nl = (li < SCLEN - 1) ? (li + 1) : (SCLEN - 1);
      u_nxt = uB[(size_t)map_pos(k, l0 + nl) << 7];
      const float4v* row = (const float4v*)&xd[li][0];
      float4v q0 = row[0];
      float accq = bias + wv.x * q0[0] + wv.y * q0[1] + wv.z * q0[2] + wv.w * q0[3];
      float dt = softplus_fast(accq);
      float dtu = dt * u;
      float4v b0 = row[1], b1 = row[2], b2 = row[3], b3 = row[4];
      float4v c0 = row[5], c1 = row[6], c2 = row[7], c3 = row[8];
      float4v e0, e1, e2, e3;
#pragma unroll
      for (int j = 0; j < 4; ++j) {
        e0[j] = exp2f(a0v[j] * dt);
        e1[j] = exp2f(a1q[j] * dt);
        e2[j] = exp2f(a2q[j] * dt);
        e3[j] = exp2f(a3q[j] * dt);
      }
      h0 = e0 * h0 + dtu * b0;
      h1 = e1 * h1 + dtu * b1;
      h2 = e2 * h2 + dtu * b2;
      h3 = e3 * h3 + dtu * b3;
      float4v sy = h0 * c0;
      sy += h1 * c1;
      sy += h2 * c2;
      sy += h3 * c3;
      yB[(size_t)(l0 + li) << 7] = f2bf((sy[0] + sy[1]) + (sy[2] + sy[3]));
    }
  }
}

// Fused: 4-direction combine (bf16 ys) + D*xxc + out_norm LN -> *silu(z) -> out_proj -> +x_res
__global__ __launch_bounds__(256) void outproj_kernel(const ushortT* __restrict__ ys16,
                                                      const float* __restrict__ xxc,
                                                      const float* __restrict__ Ds,
                                                      const float* __restrict__ z,
                                                      const float* __restrict__ ong,
                                                      const float* __restrict__ onb,
                                                      const float* __restrict__ opwt,
                                                      const float* __restrict__ xres,
                                                      float* __restrict__ x1) {
  int wv = threadIdx.x >> 6, lane = threadIdx.x & 63;
  size_t pi0 = (size_t)blockIdx.x << 4;
  __shared__ float gb[128][16];
  float og0 = ong[lane], ob0 = onb[lane];
  float og1 = ong[64 + lane], ob1 = onb[64 + lane];
  float ds0 = Ds[lane] + Ds[128 + lane] + Ds[256 + lane] + Ds[384 + lane];
  float ds1 = Ds[64 + lane] + Ds[192 + lane] + Ds[320 + lane] + Ds[448 + lane];
#pragma unroll
  for (int j = 0; j < 4; ++j) {
    int p = (wv << 2) + j;
    size_t pp = pi0 + p;
    int bl = (int)(pp >> 12);
    int pg = (int)(pp & 4095);
    int h = pg >> 6, w = pg & 63;
    int l1 = (w << 6) | h;
    size_t base = ((size_t)bl * 4) << 12;
    size_t i0 = (base + pg) << 7;
    size_t i1 = (base + 4096 + l1) << 7;
    size_t i2 = (base + 2 * 4096 + (4095 - pg)) << 7;
    size_t i3 = (base + 3 * 4096 + (4095 - l1)) << 7;
    float xx0 = xxc[(pp << 7) + lane], xx1 = xxc[(pp << 7) + 64 + lane];
    float y0 = bf2f(ys16[i0 + lane]) + bf2f(ys16[i1 + lane]) + bf2f(ys16[i2 + lane]) +
               bf2f(ys16[i3 + lane]) + xx0 * ds0;
    float y1 = bf2f(ys16[i0 + 64 + lane]) + bf2f(ys16[i1 + 64 + lane]) +
               bf2f(ys16[i2 + 64 + lane]) + bf2f(ys16[i3 + 64 + lane]) + xx1 * ds1;
    float s = wred64(y0 + y1);
    float s2 = wred64(y0 * y0 + y1 * y1);
    float m = s * (1.f / 128), var = s2 * (1.f / 128) - m * m;
    float rstd = rsqrtf(var + 1e-5f);
    float z0 = z[(pp << 7) + lane], z1 = z[(pp << 7) + 64 + lane];
    gb[lane][p] = ((y0 - m) * rstd * og0 + ob0) * silu(z0);
    gb[64 + lane][p] = ((y1 - m) * rstd * og1 + ob1) * silu(z1);
  }
  __syncthreads();
  int p0 = wv << 2;
  float4v acc = {0.f, 0.f, 0.f, 0.f};
  for (int c = 0; c < 128; ++c) {
    float w = opwt[(c << 6) + lane];
    acc += w * (*(const float4v*)&gb[c][p0]);
  }
  float accs[4];
  *(float4v*)&accs[0] = acc;
#pragma unroll
  for (int j = 0; j < 4; ++j) {
    size_t pp = pi0 + p0 + j;
    x1[pp * 64 + lane] = xres[pp * 64 + lane] + accs[j];
  }
}

// ln2 -> fc1 -> gelu(tanh) -> fc2 -> residual -> NCHW output (fused transpose)
__global__ __launch_bounds__(256) void mlp_kernel(const float* __restrict__ x1,
                                                  const float* __restrict__ g2,
                                                  const float* __restrict__ b2,
                                                  const float* __restrict__ w1t,
                                                  const float* __restrict__ bb1,
                                                  const float* __restrict__ w2t,
                                                  const float* __restrict__ bb2,
                                                  float* __restrict__ out) {
  int wv = threadIdx.x >> 6, lane = threadIdx.x & 63;
  size_t pi0 = (size_t)blockIdx.x << 4;
  __shared__ float xb[64][16], tb[64][16];
  __shared__ float ot[64][17];
  float gv = g2[lane], bv = b2[lane];
  float xsave[4];
#pragma unroll
  for (int j = 0; j < 4; ++j) {
    int p = (wv << 2) + j;
    float xv = x1[(pi0 + p) * 64 + lane];
    xsave[j] = xv;
    float s = wred64(xv), s2 = wred64(xv * xv);
    float m = s * (1.f / 64), var = s2 * (1.f / 64) - m * m;
    float rstd = rsqrtf(var + 1e-5f);
    xb[lane][p] = (xv - m) * rstd * gv + bv;
  }
  __syncthreads();
  int p0 = wv << 2;
  float bb1v = bb1[lane];
  float4v acc = {bb1v, bb1v, bb1v, bb1v};
  for (int c = 0; c < 64; ++c) {
    float w = w1t[(c << 6) + lane];
    acc += w * (*(const float4v*)&xb[c][p0]);
  }
  float us[4];
  *(float4v*)&us[0] = acc;
#pragma unroll
  for (int j = 0; j < 4; ++j) {
    float u = us[j];
    float tt = tanhf(0.7978845608028654f * (u + 0.044715f * u * u * u));
    tb[lane][p0 + j] = 0.5f * u * (1.f + tt);
  }
  __syncthreads();
  float bb2v = bb2[lane];
  float4v acc2 = {bb2v, bb2v, bb2v, bb2v};
  for (int c = 0; c < 64; ++c) {
    float w = w2t[(c << 6) + lane];
    acc2 += w * (*(const float4v*)&tb[c][p0]);
  }
  float o2[4];
  *(float4v*)&o2[0] = acc2;
#pragma unroll
  for (int j = 0; j < 4; ++j)
    ot[lane][p0 + j] = xsave[j] + o2[j];
  __syncthreads();
  int bl = (int)(pi0 >> 12);
  int pg0 = (int)(pi0 & 4095);
  int t = threadIdx.x;
  int c = t >> 2, q = t & 3;
  float4 v = make_float4(ot[c][(q << 2) + 0], ot[c][(q << 2) + 1],
                         ot[c][(q << 2) + 2], ot[c][(q << 2) + 3]);
  *(float4*)&out[(((size_t)bl * 64 + c) << 12) + pg0 + (q << 2)] = v;
}

extern "C" void kernel_launch(void* const* d_in, const int* in_sizes, int n_in,
                              void* d_out, int out_size, void* d_ws, size_t ws_size,
                              hipStream_t stream) {
  const float* img  = (const float*)d_in[0];
  const float* dz   = (const float*)d_in[1];
  const float* sg   = (const float*)d_in[2];
  const float* gn1g = (const float*)d_in[3];
  const float* gn1b = (const float*)d_in[4];
  const float* c1w  = (const float*)d_in[5];
  const float* c1b  = (const float*)d_in[6];
  const float* gn2g = (const float*)d_in[7];
  const float* gn2b = (const float*)d_in[8];
  const float* c2w  = (const float*)d_in[9];
  const float* c2b  = (const float*)d_in[10];
  const float* skw  = (const float*)d_in[11];
  const float* skb  = (const float*)d_in[12];
  const float* ln1g = (const float*)d_in[13];
  const float* ln1b = (const float*)d_in[14];
  const float* ln2g = (const float*)d_in[15];
  const float* ln2b = (const float*)d_in[16];
  const float* ipw  = (const float*)d_in[17];
  const float* dww  = (const float*)d_in[18];
  const float* dwb  = (const float*)d_in[19];
  const float* xpw  = (const float*)d_in[20];
  const float* dtw  = (const float*)d_in[21];
  const float* dtb  = (const float*)d_in[22];
  const float* Alog = (const float*)d_in[23];
  const float* Dsp  = (const float*)d_in[24];
  const float* ong  = (const float*)d_in[25];
  const float* onb  = (const float*)d_in[26];
  const float* opw  = (const float*)d_in[27];
  const float* f1w  = (const float*)d_in[28];
  const float* f1b  = (const float*)d_in[29];
  const float* f2w  = (const float*)d_in[30];
  const float* f2b  = (const float*)d_in[31];

  float* out = (float*)d_out;
  float* ws = (float*)d_ws;
  if (ws_size < F_TOTAL * sizeof(float)) return;

  float* h1    = ws + F_H1;
  float* h2    = ws + F_H2;
  float* xres  = ws + F_XRES;
  float* xxin  = ws + F_XXIN;
  float* zbuf  = ws + F_Z;
  float* xxc   = ws + F_XXC;
  float* xdbl  = ws + F_XDBL;
  float* x1    = ws + F_X1;
  float* stats = ws + F_STATS;
  ushortT* act1b = (ushortT*)(ws + F_ACT1);
  ushortT* act2b = (ushortT*)(ws + F_ACT2);
  // stats partials in X2 region
  double* part  = (double*)(ws + F_X2);                    // up to 640 doubles
  // all prepped weights in WTS region
  float* wt_sk = ws + F_WTS;                               // 12288
  float* wt_ip = ws + F_WTS + 16384;                       // 16384
  float* wt_op = ws + F_WTS + 32768;                       // 8192
  float* wt_f1 = ws + F_WTS + 40960;                       // 4096
  float* wt_f2 = ws + F_WTS + 45056;                       // 4096
  ushortT* wb1 = (ushortT*)(ws + F_WTS + 49152);           // 110592 ushorts
  ushortT* wb2 = wb1 + 110592;                             // 36864 ushorts
  // scan arrays in YS region: ys bf16 | chunkH bf16 | sdt f32
  ushortT* ys16     = (ushortT*)(ws + F_YS);
  ushortT* chunkH16 = (ushortT*)(ws + F_YS + 6291456);
  float*   chunkSdt = ws + F_YS + 6291456 + 3145728;
  ushortT* chunkHS16 = (ushortT*)(ws + F_XCAT);            // XCAT region is free scratch

  // all weight prep in one launch (no deps)
  prep_kernel<<<752, 256, 0, stream>>>(skw, ipw, opw, f1w, f2w, c1w, c2w,
                                       wt_sk, wt_ip, wt_op, wt_f1, wt_f2, wb1, wb2);
  // batched sums over img(6)+dz(2)+sg(2)
  stats1_all_kernel<<<320, 256, 0, stream>>>(img, dz, sg, part);
  // img instance stats + analytic gn1 cat stats
  stats2_comb_kernel<<<7, 64, 0, stream>>>(part, stats);
  // gn1 + silu over virtual concat -> NHWC bf16
  gnsilu_cat_kernel<<<NBL * 64, 256, 0, stream>>>(img, dz, sg, gn1g, gn1b, stats, act1b);
  conv_mfma_kernel<NC3><<<NBL * 64 * 2, 256, 0, stream>>>(act1b, wb1, c1b, h1);
  // gn2 + silu -> NHWC bf16
  stats1_kernel<<<NBL * 32, 256, 0, stream>>>(h1, NC * NHW, part);
  stats2_kernel<<<NBL, 64, 0, stream>>>(part, NC * NHW, stats + 32, stats + 40);
  gnsilu_t_kernel<<<NBL * 64, 256, 0, stream>>>(h1, gn2g, gn2b, stats + 32, act2b);
  conv_mfma_kernel<NC><<<NBL * 64 * 2, 256, 0, stream>>>(act2b, wb2, c2b, h2);
  // skip 1x1 (virtual concat) + residual + NHWC transpose
  skip_kernel<<<NBL * 64, 256, 0, stream>>>(img, dz, sg, stats, h2, wt_sk, skb, xres);
  // SS2D
  inproj_kernel<<<1536, 256, 0, stream>>>(xres, ln1g, ln1b, wt_ip, xxin, zbuf);
  dwconv_kernel<<<12288, 256, 0, stream>>>(xxin, dww, dwb, xxc);
  xdbl_kernel<<<NBL * 2 * 64, 256, 0, stream>>>(xxc, xpw, xdbl);
  // chunked scan (128 chunks of 32); H/HS/ys in bf16
  scan_pass1_kernel<<<24 * NCH, 128, 0, stream>>>(xdbl, xxc, dtw, dtb, Alog, chunkSdt, chunkH16);
  scan_pass2_kernel<<<192, 256, 0, stream>>>(chunkSdt, chunkH16, Alog, chunkHS16);
  scan_pass3_kernel<<<24 * NCH, 128, 0, stream>>>(xdbl, xxc, dtw, dtb, Alog, chunkHS16, ys16);
  // fused combine + out_norm + gate + out_proj + residual
  outproj_kernel<<<1536, 256, 0, stream>>>(ys16, xxc, Dsp, zbuf, ong, onb, wt_op, xres, x1);
  // MLP + residual + fused NCHW output transpose
  mlp_kernel<<<1536, 256, 0, stream>>>(x1, ln2g, ln2b, wt_f1, f1b, wt_f2, f2b, out);
}